// Round 8
// baseline (4741.385 us; speedup 1.0000x reference)
//
#include <hip/hip_runtime.h>

constexpr int B = 2, S = 1024, D = 512, H = 8, F = 3072, TOPK = 64;

typedef unsigned short u16;
typedef unsigned int u32;
typedef __attribute__((ext_vector_type(8))) short bfrag;    // 8 bf16 (4 VGPR)
typedef __attribute__((ext_vector_type(4))) float f32x4;

__device__ __forceinline__ u16 f2bf_rn(float x) {
  u32 u = __float_as_uint(x);
  u32 r = (u + 0x7FFFu + ((u >> 16) & 1u)) >> 16;
  return (u16)r;
}
__device__ __forceinline__ float bf2f(u16 h) {
  return __uint_as_float(((u32)h) << 16);
}

#define GLOAD_LDS16(gp, lp)                                                   \
  __builtin_amdgcn_global_load_lds(                                           \
      (const __attribute__((address_space(1))) u32*)(gp),                     \
      (__attribute__((address_space(3))) u32*)(lp), 16, 0, 0)

// ---- stage one 128x32 bf16 tile (8KB) into LDS, granule-swizzled ----
// LDS slot s (16B granules): row = s>>2, slot sl = s&3 holds global k-granule
// sl ^ ((row>>1)&3). Write side linear (gload_lds); permutation applied on the
// per-lane GLOBAL source address (rule 21: both-sides involution).
// 128-thread blocks: each thread stages 4 granules per tile.
__device__ __forceinline__ void stage_tile2(const u16* __restrict__ g, int r0,
                                            int ld, int k0, u16* lds,
                                            int w, int lane) {
#pragma unroll
  for (int p = 0; p < 4; ++p) {
    const int slot = p * 128 + w * 64 + lane;
    const int row = slot >> 2, sl = slot & 3;
    const int gr = sl ^ ((row >> 1) & 3);
    const u16* gp = g + (long)(r0 + row) * ld + k0 + gr * 8;
    u16* lp = lds + (p * 128 + w * 64) * 8;  // wave-uniform base; +lane*16B auto
    GLOAD_LDS16(gp, lp);
  }
}

// read fragment: lane group lg holds global k-granule lg of `row`
__device__ __forceinline__ bfrag frag_at(const u16* tile, int row, int lg) {
  const int idx = row * 32 + ((lg ^ ((row >> 1) & 3)) << 3);
  return *(const bfrag*)(tile + idx);
}

// ============ split-bf16 NT MFMA GEMM v4: 128x64 wave tiles ============
// C[M,N] (+)= A[M,K] @ Bt[N,K]^T, operands as bf16 hi/lo pairs.
// 3-product AhBh+AhBl+AlBh, f32 MFMA accum. 128x128 block, BK=32,
// 2 waves of 128 threads; each wave owns 128 rows x 64 cols -> 24 ds_read
// feeding 96 MFMA per K-step (1.33x FLOP/LDS-byte vs 64x64 tiles; the
// round-7 counters proved LDS read throughput is the binding pipe).
// Double-buffered LDS (64KB -> 2 blocks/CU preserved).
// 1D grid with bijective XCD swizzle; z -> (zb = z%NB, zh = z/NB) offsets.
template<bool ACCUM, bool CAUSAL, bool MASK, bool OUTPAIR>
__global__ __launch_bounds__(128) void gemm_split3(
    const u16* __restrict__ Ah0, const u16* __restrict__ Al0,
    const u16* __restrict__ Bh0, const u16* __restrict__ Bl0,
    float* __restrict__ C, u16* __restrict__ Ch, u16* __restrict__ Cl,
    const float* __restrict__ mask0, const float* __restrict__ mask1, int ldm,
    int K, int lda, int ldb, int ldc, int gx, int gy, int NB,
    long sAb, long sAh, long sBb, long sBh, long sCb, long sCh)
{
  __shared__ u16 smem[32768];  // 2 bufs x 4 tiles x 4096 u16 = 64 KB

  // bijective XCD swizzle (m204)
  const int nwg = gridDim.x;
  const int q = nwg >> 3, r = nwg & 7;
  const int xcd = blockIdx.x & 7, lid = blockIdx.x >> 3;
  const int sw = (xcd < r ? xcd * (q + 1) : r * (q + 1) + (xcd - r) * q) + lid;
  const int gxy = gx * gy;
  const int z = sw / gxy;
  const int rem = sw - z * gxy;
  const int by = rem / gx;
  const int bx = rem - by * gx;
  const int zb = z % NB, zh = z / NB;

  const u16* Ahp = Ah0 + zb * sAb + zh * sAh;
  const u16* Alp = Al0 + zb * sAb + zh * sAh;
  const u16* Bhp = Bh0 + zb * sBb + zh * sBh;
  const u16* Blp = Bl0 + zb * sBb + zh * sBh;
  const long coff = zb * sCb + zh * sCh;

  const int bm = by * 128, bn = bx * 128;
  const int tid = threadIdx.x;
  const int lane = tid & 63, w = tid >> 6;   // w in {0,1}: B-column half
  const int lg = lane >> 4, lr = lane & 15;

  f32x4 acc[8][4];
#pragma unroll
  for (int i = 0; i < 8; ++i)
#pragma unroll
    for (int j = 0; j < 4; ++j) {
      acc[i][j][0] = 0.f; acc[i][j][1] = 0.f;
      acc[i][j][2] = 0.f; acc[i][j][3] = 0.f;
    }

  const int kmax = CAUSAL ? min(K, bm + 128) : K;
  const int nt = kmax >> 5;

#define STAGE(buf, k0)                                        \
  do {                                                        \
    u16* base_ = smem + (buf) * 16384;                        \
    stage_tile2(Ahp, bm, lda, (k0), base_,         w, lane);  \
    stage_tile2(Alp, bm, lda, (k0), base_ + 4096,  w, lane);  \
    stage_tile2(Bhp, bn, ldb, (k0), base_ + 8192,  w, lane);  \
    stage_tile2(Blp, bn, ldb, (k0), base_ + 12288, w, lane);  \
  } while (0)

  STAGE(0, 0);
  for (int t = 0; t < nt; ++t) {
    const int cur = t & 1;
    __syncthreads();                       // drains prior stage (vmcnt 0)
    if (t + 1 < nt) STAGE(cur ^ 1, (t + 1) << 5);  // overlaps with compute
    const u16* bufp = smem + cur * 16384;
    bfrag bh4[4], bl4[4];
#pragma unroll
    for (int j = 0; j < 4; ++j) {
      const int rowB = w * 64 + j * 16 + lr;
      bh4[j] = frag_at(bufp + 8192,  rowB, lg);
      bl4[j] = frag_at(bufp + 12288, rowB, lg);
    }
#pragma unroll
    for (int i = 0; i < 8; ++i) {
      const int rowA = i * 16 + lr;
      const bfrag ah = frag_at(bufp,        rowA, lg);
      const bfrag al = frag_at(bufp + 4096, rowA, lg);
#pragma unroll
      for (int j = 0; j < 4; ++j) {
        acc[i][j] = __builtin_amdgcn_mfma_f32_16x16x32_bf16(ah, bh4[j], acc[i][j], 0, 0, 0);
        acc[i][j] = __builtin_amdgcn_mfma_f32_16x16x32_bf16(ah, bl4[j], acc[i][j], 0, 0, 0);
        acc[i][j] = __builtin_amdgcn_mfma_f32_16x16x32_bf16(al, bh4[j], acc[i][j], 0, 0, 0);
      }
    }
  }
#undef STAGE

  // epilogue: C/D layout col = lane&15, row = (lane>>4)*4 + reg
  const float* mp_ = MASK ? (zh ? mask1 : mask0) : nullptr;
#pragma unroll
  for (int i = 0; i < 8; ++i)
#pragma unroll
    for (int j = 0; j < 4; ++j)
#pragma unroll
      for (int rr = 0; rr < 4; ++rr) {
        const int row = bm + i * 16 + lg * 4 + rr;
        const int col = bn + w * 64 + j * 16 + lr;
        float v = acc[i][j][rr];
        if (MASK) v *= mp_[(long)row * ldm + col];
        const long ci = coff + (long)row * ldc + col;
        if (OUTPAIR) {
          const u16 h = f2bf_rn(v);
          Ch[ci] = h;
          Cl[ci] = f2bf_rn(v - bf2f(h));
        } else if (ACCUM) {
          C[ci] += v;
        } else {
          C[ci] = v;
        }
      }
}

// ================= small kernels =================
__global__ void split_pair(const float* __restrict__ in, u16* __restrict__ oh,
                           u16* __restrict__ ol, long n) {
  for (long i = blockIdx.x * (long)blockDim.x + threadIdx.x; i < n;
       i += gridDim.x * (long)blockDim.x) {
    const float x = in[i];
    const u16 h = f2bf_rn(x);
    oh[i] = h;
    ol[i] = f2bf_rn(x - bf2f(h));
  }
}

// probs[:, h] (both b) split into a contiguous [b][S][S] pair
__global__ void split_pair_probs(const float* __restrict__ probs, int h,
                                 u16* __restrict__ oh, u16* __restrict__ ol) {
  const long n = (long)B << 20;  // B * S * S, S*S = 2^20
  for (long i = blockIdx.x * (long)blockDim.x + threadIdx.x; i < n;
       i += gridDim.x * (long)blockDim.x) {
    const long b = i >> 20;
    const long rr = i & ((1L << 20) - 1);
    const float x = probs[(b * H + h) * (1L << 20) + rr];
    const u16 hh = f2bf_rn(x);
    oh[i] = hh;
    ol[i] = f2bf_rn(x - bf2f(hh));
  }
}

// out pair [C][R] = transpose of in [R][C], optional per-input-row divisor
__global__ __launch_bounds__(256) void transpose_split(
    const float* __restrict__ in, const float* __restrict__ divv,
    u16* __restrict__ oh, u16* __restrict__ ol, int R, int C) {
  __shared__ float t[32][33];
  const int bx = blockIdx.x * 32;  // C dim
  const int by = blockIdx.y * 32;  // R dim
  const int x = threadIdx.x & 31, y = threadIdx.x >> 5;
#pragma unroll
  for (int j = 0; j < 4; ++j) {
    const int rr = by + y + j * 8;
    float v = in[(long)rr * C + bx + x];
    if (divv) v /= divv[rr];
    t[y + j * 8][x] = v;
  }
  __syncthreads();
#pragma unroll
  for (int j = 0; j < 4; ++j) {
    const int c = bx + y + j * 8;
    const float v = t[x][y + j * 8];
    const u16 h = f2bf_rn(v);
    oh[(long)c * R + by + x] = h;
    ol[(long)c * R + by + x] = f2bf_rn(v - bf2f(h));
  }
}

__global__ void cvec_partial(const float* __restrict__ W_OV,
                             const float* __restrict__ ub1,
                             const float* __restrict__ ub2,
                             float* __restrict__ ctmp) {
  const int o = blockIdx.x * 256 + threadIdx.x;
  const int h = blockIdx.y;
  const float* W = W_OV + (long)h * D * D;
  float acc = 0.f;
  for (int i = 0; i < D; ++i)
    acc = fmaf(W[(long)i * D + o], ub1[i] + ub2[i], acc);
  ctmp[h * D + o] = acc;
}

__global__ void cvec_reduce(const float* __restrict__ ctmp, float* __restrict__ cvec) {
  const int o = blockIdx.x * blockDim.x + threadIdx.x;
  if (o < D) {
    float a = 0.f;
    for (int h = 0; h < H; ++h) a += ctmp[h * D + o];
    cvec[o] = a;
  }
}

__global__ __launch_bounds__(64) void bias_vec(
    const float* __restrict__ enc_w, const float* __restrict__ b_O,
    const float* __restrict__ b_dec, const float* __restrict__ enc_b,
    const float* __restrict__ cvec, float* __restrict__ bias0,
    float* __restrict__ evec) {
  const int f = blockIdx.x;
  const int l = threadIdx.x;
  float s1 = 0.f, s2 = 0.f;
  for (int o = l; o < D; o += 64) {
    const float w = enc_w[(long)f * D + o];
    s1 = fmaf(w, b_O[o] - b_dec[o], s1);
    s2 = fmaf(w, cvec[o], s2);
  }
  for (int off = 32; off > 0; off >>= 1) {
    s1 += __shfl_down(s1, off);
    s2 += __shfl_down(s2, off);
  }
  if (l == 0) { bias0[f] = s1 + enc_b[f]; evec[f] = s2; }
}

__global__ __launch_bounds__(256) void transpose_dw(const float* __restrict__ in,
                                                    float* __restrict__ out) {
  __shared__ float t[32][33];
  const int bx = blockIdx.x * 32;
  const int by = blockIdx.y * 32;
  const int x = threadIdx.x & 31, y = threadIdx.x >> 5;
#pragma unroll
  for (int j = 0; j < 4; ++j) {
    const int row = y + j * 8;
    t[row][x] = in[(long)(by + row) * F + bx + x];
  }
  __syncthreads();
#pragma unroll
  for (int j = 0; j < 4; ++j) {
    const int row = y + j * 8;
    out[(long)(bx + row) * D + by + x] = t[x][row];
  }
}

// top-64 of (bias0 + evec/ln + featP) per row, IN PLACE: read row, zero it,
// relu+scatter top-64 back; record (v,idx) for recon.
__global__ __launch_bounds__(256) void topk_fused(
    float* __restrict__ featP, const float* __restrict__ bias0,
    const float* __restrict__ evec, const float* __restrict__ ln,
    float* __restrict__ topv, int* __restrict__ topi) {
  const int row = blockIdx.x;  // b*S+s
  const float rln = 1.f / ln[row];
  float* p0 = featP + (long)row * F;
  __shared__ float vals[F];
  __shared__ float rv[256];
  __shared__ int ri[256];
  for (int j = threadIdx.x; j < F; j += 256)
    vals[j] = bias0[j] + evec[j] * rln + p0[j];
  __syncthreads();
  for (int j = threadIdx.x; j < F; j += 256) p0[j] = 0.f;
  __syncthreads();
  for (int it = 0; it < TOPK; ++it) {
    float best = -3.4e38f;
    int bi = F;
    for (int j = threadIdx.x; j < F; j += 256) {
      const float v = vals[j];
      if (v > best) { best = v; bi = j; }  // strict > keeps lowest index
    }
    rv[threadIdx.x] = best; ri[threadIdx.x] = bi;
    __syncthreads();
    for (int s2 = 128; s2 > 0; s2 >>= 1) {
      if (threadIdx.x < s2) {
        const float ov = rv[threadIdx.x + s2];
        const int oi = ri[threadIdx.x + s2];
        if (ov > rv[threadIdx.x] ||
            (ov == rv[threadIdx.x] && oi < ri[threadIdx.x])) {
          rv[threadIdx.x] = ov; ri[threadIdx.x] = oi;
        }
      }
      __syncthreads();
    }
    if (threadIdx.x == 0) {
      const int idx = ri[0];
      const float v = fmaxf(rv[0], 0.f);
      p0[idx] = v;
      topv[row * TOPK + it] = v;
      topi[row * TOPK + it] = idx;
      vals[idx] = -3.4e38f;
    }
    __syncthreads();
  }
}

__global__ __launch_bounds__(256) void recon_kernel(
    const float* __restrict__ topv, const int* __restrict__ topi,
    const float* __restrict__ dec_wT, const float* __restrict__ b_dec,
    float* __restrict__ recon) {
  const int row = blockIdx.x;
  __shared__ float sv[TOPK];
  __shared__ int si[TOPK];
  if (threadIdx.x < TOPK) {
    sv[threadIdx.x] = topv[row * TOPK + threadIdx.x];
    si[threadIdx.x] = topi[row * TOPK + threadIdx.x];
  }
  __syncthreads();
  const int d0 = threadIdx.x, d1 = threadIdx.x + 256;
  float a0 = b_dec[d0], a1 = b_dec[d1];
  for (int j = 0; j < TOPK; ++j) {
    const float v = sv[j];
    const float* wp = dec_wT + (long)si[j] * D;
    a0 = fmaf(v, wp[d0], a0);
    a1 = fmaf(v, wp[d1], a1);
  }
  recon[(long)row * D + d0] = a0;
  recon[(long)row * D + d1] = a1;
}

// ================= launch =================
extern "C" void kernel_launch(void* const* d_in, const int* in_sizes, int n_in,
                              void* d_out, int out_size, void* d_ws, size_t ws_size,
                              hipStream_t stream) {
  const float* resid = (const float*)d_in[0];
  const float* ln    = (const float*)d_in[1];
  const float* probs = (const float*)d_in[2];
  const float* W_OV  = (const float*)d_in[3];
  const float* b_O   = (const float*)d_in[4];
  const float* enc_w = (const float*)d_in[5];
  const float* enc_b = (const float*)d_in[6];
  const float* b_dec = (const float*)d_in[7];
  const float* dec_w = (const float*)d_in[8];
  const float* up_dec_[2]  = {(const float*)d_in[9], (const float*)d_in[13]};
  const float* up_bdec_[2] = {(const float*)d_in[10], (const float*)d_in[14]};
  const float* pf_[2]      = {(const float*)d_in[11], (const float*)d_in[15]};
  const float* mask_[2]    = {(const float*)d_in[12], (const float*)d_in[16]};

  float* out_feat  = (float*)d_out;   // doubles as the dense P accumulator
  float* out_recon = out_feat + (size_t)B * S * F;
  float* P = out_feat;

  constexpr int NALL = D + 2 * F;   // 6656 = 52*128
  constexpr int NB0  = D + F;       // 3584: B0 = [Eh | vw_u] columns
  // ---- workspace layout: 189.8 MB (< 191.9 MB proven in round 2) ----
  float* ws = (float*)d_ws;
  size_t o = 0;
  float* bias0 = ws + o; o += F;
  float* evec  = ws + o; o += F;
  float* cvec  = ws + o; o += D;
  float* ctmp  = ws + o; o += (size_t)H * D;
  float* topv  = ws + o; o += (size_t)B * S * TOPK;
  int*   topi  = (int*)(ws + o); o += (size_t)B * S * TOPK;
  u16* encwPh = (u16*)(ws + o); o += (size_t)F * D / 2;
  u16* encwPl = (u16*)(ws + o); o += (size_t)F * D / 2;
  u16* wovPh  = (u16*)(ws + o); o += (size_t)H * D * D / 2;
  u16* wovPl  = (u16*)(ws + o); o += (size_t)H * D * D / 2;
  u16* udTh   = (u16*)(ws + o); o += (size_t)2 * F * D / 2;       // [u][F][D]
  u16* udTl   = (u16*)(ws + o); o += (size_t)2 * F * D / 2;
  u16* Gallh  = (u16*)(ws + o); o += (size_t)B * NALL * S / 2;    // [b][6656][S]
  u16* Galll  = (u16*)(ws + o); o += (size_t)B * NALL * S / 2;
  u16* Phh    = (u16*)(ws + o); o += (size_t)B * S * S / 2;       // per-h probs
  u16* Phl    = (u16*)(ws + o); o += (size_t)B * S * S / 2;
  u16* B0h    = (u16*)(ws + o); o += (size_t)F * NB0 / 2;         // [d][3584]
  u16* B0l    = (u16*)(ws + o); o += (size_t)F * NB0 / 2;
  const size_t xoff = o;                                          // dec_wT alias
  u16* Xallh  = (u16*)(ws + o); o += (size_t)B * S * NALL / 2;    // [b][q][6656]
  u16* Xalll  = (u16*)(ws + o); o += (size_t)B * S * NALL / 2;
  float* dec_wT = ws + xoff;  // used only after h-loop (Xall dead by then)

  hipMemsetAsync(P, 0, sizeof(float) * (size_t)B * S * F, stream);

  // ---- operand prep ----
  split_pair<<<1024, 256, 0, stream>>>(enc_w, encwPh, encwPl, (long)F * D);
  split_pair<<<1024, 256, 0, stream>>>(W_OV, wovPh, wovPl, (long)H * D * D);
  for (int b = 0; b < B; ++b) {
    // Gall rows 0..511 = resid^T/ln
    transpose_split<<<dim3(D / 32, S / 32), 256, 0, stream>>>(
        resid + (size_t)b * S * D, ln + (size_t)b * S,
        Gallh + ((size_t)b * NALL + 0) * S, Galll + ((size_t)b * NALL + 0) * S,
        S, D);
    // Gall rows 512+u*3072 .. = pf_u^T/ln
    for (int u = 0; u < 2; ++u)
      transpose_split<<<dim3(F / 32, S / 32), 256, 0, stream>>>(
          pf_[u] + (size_t)b * S * F, ln + (size_t)b * S,
          Gallh + ((size_t)b * NALL + 512 + (size_t)u * F) * S,
          Galll + ((size_t)b * NALL + 512 + (size_t)u * F) * S, S, F);
  }
  for (int u = 0; u < 2; ++u)
    transpose_split<<<dim3(F / 32, D / 32), 256, 0, stream>>>(
        up_dec_[u], nullptr, udTh + (size_t)u * F * D, udTl + (size_t)u * F * D,
        D, F);
  cvec_partial<<<dim3(2, 8), 256, 0, stream>>>(W_OV, up_bdec_[0], up_bdec_[1], ctmp);
  cvec_reduce<<<2, 256, 0, stream>>>(ctmp, cvec);
  bias_vec<<<F, 64, 0, stream>>>(enc_w, b_O, b_dec, enc_b, cvec, bias0, evec);

  // ---- per-head pipeline ----
  for (int h = 0; h < H; ++h) {
    // probs[:,h] split pair (both b, one dispatch)
    split_pair_probs<<<2048, 256, 0, stream>>>(probs, h, Phh, Phl);
    // Eh[f,i] -> B0 cols 0..511 (ldc = 3584)
    gemm_split3<false, false, false, true><<<96, 128, 0, stream>>>(
        encwPh, encwPl, wovPh + (size_t)h * D * D, wovPl + (size_t)h * D * D,
        nullptr, B0h, B0l, nullptr, nullptr, 0,
        512, 512, 512, NB0, 4, 24, 1, 0L, 0L, 0L, 0L, 0L, 0L);
    // Xall[b][q][0:6656] = probs_h[b] @ Gall[b]^T (causal) -> pair, ldc=6656
    gemm_split3<false, true, false, true><<<832, 128, 0, stream>>>(
        Phh, Phl, Gallh, Galll, nullptr, Xallh, Xalll, nullptr, nullptr, 0,
        S, S, S, NALL, NALL / 128, 8, 2,
        (long)S * S, 0L, (long)NALL * S, 0L, (long)S * NALL, 0L);

    for (int u = 0; u < 2; ++u) {
      // vw_u[d][n] = (Eh @ udT_u^T) * mask_u -> B0 cols 512..3583 (ldc=3584)
      // A-operand = Eh read back from B0 cols 0..511 (lda = 3584).
      gemm_split3<false, false, true, true><<<576, 128, 0, stream>>>(
          B0h, B0l, udTh + (size_t)u * F * D, udTl + (size_t)u * F * D,
          nullptr, B0h + 512, B0l + 512, mask_[u], nullptr, F,
          512, NB0, D, NB0, 24, 24, 1, 0L, 0L, 0L, 0L, 0L, 0L);
      if (u == 0) {
        // P[b] += Xall[:, 0:3584] @ B0^T   (K=3584: Xact@Eh^T + X_u0@vw^T)
        gemm_split3<true, false, false, false><<<384, 128, 0, stream>>>(
            Xallh, Xalll, B0h, B0l, P, nullptr, nullptr, nullptr, nullptr, 0,
            NB0, NALL, NB0, F, 24, 8, 2,
            (long)S * NALL, 0L, 0L, 0L, (long)S * F, 0L);
      } else {
        // P[b] += Xall[:, 3584:6656] @ vw_u1^T  (K=3072, B at B0+512, ldb=3584)
        gemm_split3<true, false, false, false><<<384, 128, 0, stream>>>(
            Xallh + NB0, Xalll + NB0, B0h + 512, B0l + 512,
            P, nullptr, nullptr, nullptr, nullptr, 0,
            3072, NALL, NB0, F, 24, 8, 2,
            (long)S * NALL, 0L, 0L, 0L, (long)S * F, 0L);
      }
    }
  }

  // ---- tail: dec_w transpose (into dead Xall region), topk in-place, recon ----
  transpose_dw<<<dim3(F / 32, D / 32), 256, 0, stream>>>(dec_w, dec_wT);
  topk_fused<<<B * S, 256, 0, stream>>>(P, bias0, evec, ln, topv, topi);
  recon_kernel<<<B * S, 256, 0, stream>>>(topv, topi, dec_wT, b_dec, out_recon);
}

// Round 10
// 4237.532 us; speedup vs baseline: 1.1189x; 1.1189x over previous
//
#include <hip/hip_runtime.h>

constexpr int B = 2, S = 1024, D = 512, H = 8, F = 3072, TOPK = 64;

typedef unsigned short u16;
typedef unsigned int u32;
typedef __attribute__((ext_vector_type(8))) short bfrag;    // 8 bf16 (4 VGPR)
typedef __attribute__((ext_vector_type(4))) float f32x4;

__device__ __forceinline__ u16 f2bf_rn(float x) {
  u32 u = __float_as_uint(x);
  u32 r = (u + 0x7FFFu + ((u >> 16) & 1u)) >> 16;
  return (u16)r;
}
__device__ __forceinline__ float bf2f(u16 h) {
  return __uint_as_float(((u32)h) << 16);
}

#define GLOAD_LDS16(gp, lp)                                                   \
  __builtin_amdgcn_global_load_lds(                                           \
      (const __attribute__((address_space(1))) u32*)(gp),                     \
      (__attribute__((address_space(3))) u32*)(lp), 16, 0, 0)

// ---- stage one 128x32 bf16 tile (8KB) into LDS, granule-swizzled ----
// LDS slot s (16B granules): row = s>>2, slot sl = s&3 holds global k-granule
// sl ^ ((row>>1)&3). Write side linear (gload_lds); permutation applied on the
// per-lane GLOBAL source address (rule 21: both-sides involution).
__device__ __forceinline__ void stage_tile2(const u16* __restrict__ g, int r0,
                                            int ld, int k0, u16* lds,
                                            int w, int lane) {
#pragma unroll
  for (int p = 0; p < 2; ++p) {
    const int slot = w * 128 + p * 64 + lane;
    const int row = slot >> 2, sl = slot & 3;
    const int gr = sl ^ ((row >> 1) & 3);
    const u16* gp = g + (long)(r0 + row) * ld + k0 + gr * 8;
    u16* lp = lds + (w * 128 + p * 64) * 8;  // wave-uniform base; +lane*16B auto
    GLOAD_LDS16(gp, lp);
  }
}

// read fragment: lane group lg holds global k-granule lg of `row`
__device__ __forceinline__ bfrag frag_at(const u16* tile, int row, int lg) {
  const int idx = row * 32 + ((lg ^ ((row >> 1) & 3)) << 3);
  return *(const bfrag*)(tile + idx);
}

// ============ split-bf16 NT MFMA GEMM (round-7 proven, verbatim) ============
// C[M,N] (+)= A[M,K] @ Bt[N,K]^T, operands as bf16 hi/lo pairs.
// 3-product AhBh+AhBl+AlBh, f32 MFMA accum — ALL paths (r6/r9 proved the
// top-k boundary gap is below 1p noise; precision stays at 3p, period).
// 128x128 block, BK=32, 4 waves (2x2 of 64x64). Double-buffered LDS (64KB),
// one __syncthreads per K-step, next stage issued before reads of current.
// 1D grid with bijective XCD swizzle; z -> (zb = z%NB, zh = z/NB) offsets.
template<bool ACCUM, bool CAUSAL, bool MASK, bool OUTPAIR>
__global__ __launch_bounds__(256) void gemm_split3(
    const u16* __restrict__ Ah0, const u16* __restrict__ Al0,
    const u16* __restrict__ Bh0, const u16* __restrict__ Bl0,
    float* __restrict__ C, u16* __restrict__ Ch, u16* __restrict__ Cl,
    const float* __restrict__ mask0, const float* __restrict__ mask1, int ldm,
    int K, int lda, int ldb, int ldc, int gx, int gy, int NB,
    long sAb, long sAh, long sBb, long sBh, long sCb, long sCh)
{
  __shared__ u16 smem[32768];  // 2 bufs x 4 tiles x 4096 u16 = 64 KB

  // bijective XCD swizzle (m204)
  const int nwg = gridDim.x;
  const int q = nwg >> 3, r = nwg & 7;
  const int xcd = blockIdx.x & 7, lid = blockIdx.x >> 3;
  const int sw = (xcd < r ? xcd * (q + 1) : r * (q + 1) + (xcd - r) * q) + lid;
  const int gxy = gx * gy;
  const int z = sw / gxy;
  const int rem = sw - z * gxy;
  const int by = rem / gx;
  const int bx = rem - by * gx;
  const int zb = z % NB, zh = z / NB;

  const u16* Ahp = Ah0 + zb * sAb + zh * sAh;
  const u16* Alp = Al0 + zb * sAb + zh * sAh;
  const u16* Bhp = Bh0 + zb * sBb + zh * sBh;
  const u16* Blp = Bl0 + zb * sBb + zh * sBh;
  const long coff = zb * sCb + zh * sCh;

  const int bm = by * 128, bn = bx * 128;
  const int tid = threadIdx.x;
  const int lane = tid & 63, w = tid >> 6;
  const int wr = w >> 1, wc = w & 1;
  const int lg = lane >> 4, lr = lane & 15;

  f32x4 acc[4][4];
#pragma unroll
  for (int i = 0; i < 4; ++i)
#pragma unroll
    for (int j = 0; j < 4; ++j) {
      acc[i][j][0] = 0.f; acc[i][j][1] = 0.f;
      acc[i][j][2] = 0.f; acc[i][j][3] = 0.f;
    }

  const int kmax = CAUSAL ? min(K, bm + 128) : K;
  const int nt = kmax >> 5;

#define STAGE(buf, k0)                                        \
  do {                                                        \
    u16* base_ = smem + (buf) * 16384;                        \
    stage_tile2(Ahp, bm, lda, (k0), base_,         w, lane);  \
    stage_tile2(Alp, bm, lda, (k0), base_ + 4096,  w, lane);  \
    stage_tile2(Bhp, bn, ldb, (k0), base_ + 8192,  w, lane);  \
    stage_tile2(Blp, bn, ldb, (k0), base_ + 12288, w, lane);  \
  } while (0)

  STAGE(0, 0);
  for (int t = 0; t < nt; ++t) {
    const int cur = t & 1;
    __syncthreads();                       // drains prior stage (vmcnt 0)
    if (t + 1 < nt) STAGE(cur ^ 1, (t + 1) << 5);  // overlaps with compute
    const u16* bufp = smem + cur * 16384;
    bfrag ah[4], al4[4], bh4[4], bl4[4];
#pragma unroll
    for (int i = 0; i < 4; ++i) {
      const int rowA = wr * 64 + i * 16 + lr;
      const int rowB = wc * 64 + i * 16 + lr;
      ah[i]  = frag_at(bufp,          rowA, lg);
      al4[i] = frag_at(bufp + 4096,   rowA, lg);
      bh4[i] = frag_at(bufp + 8192,   rowB, lg);
      bl4[i] = frag_at(bufp + 12288,  rowB, lg);
    }
#pragma unroll
    for (int i = 0; i < 4; ++i)
#pragma unroll
      for (int j = 0; j < 4; ++j) {
        acc[i][j] = __builtin_amdgcn_mfma_f32_16x16x32_bf16(ah[i],  bh4[j], acc[i][j], 0, 0, 0);
        acc[i][j] = __builtin_amdgcn_mfma_f32_16x16x32_bf16(ah[i],  bl4[j], acc[i][j], 0, 0, 0);
        acc[i][j] = __builtin_amdgcn_mfma_f32_16x16x32_bf16(al4[i], bh4[j], acc[i][j], 0, 0, 0);
      }
  }
#undef STAGE

  // epilogue: C/D layout col = lane&15, row = (lane>>4)*4 + reg
  const float* mp_ = MASK ? (zh ? mask1 : mask0) : nullptr;
#pragma unroll
  for (int i = 0; i < 4; ++i)
#pragma unroll
    for (int j = 0; j < 4; ++j)
#pragma unroll
      for (int rr = 0; rr < 4; ++rr) {
        const int row = bm + wr * 64 + i * 16 + lg * 4 + rr;
        const int col = bn + wc * 64 + j * 16 + lr;
        float v = acc[i][j][rr];
        if (MASK) v *= mp_[(long)row * ldm + col];
        const long ci = coff + (long)row * ldc + col;
        if (OUTPAIR) {
          const u16 h = f2bf_rn(v);
          Ch[ci] = h;
          Cl[ci] = f2bf_rn(v - bf2f(h));
        } else if (ACCUM) {
          C[ci] += v;
        } else {
          C[ci] = v;
        }
      }
}

// ================= small kernels =================
__global__ void split_pair(const float* __restrict__ in, u16* __restrict__ oh,
                           u16* __restrict__ ol, long n) {
  for (long i = blockIdx.x * (long)blockDim.x + threadIdx.x; i < n;
       i += gridDim.x * (long)blockDim.x) {
    const float x = in[i];
    const u16 h = f2bf_rn(x);
    oh[i] = h;
    ol[i] = f2bf_rn(x - bf2f(h));
  }
}

// probs[:, h] (both b) split into a contiguous [b][S][S] pair
__global__ void split_pair_probs(const float* __restrict__ probs, int h,
                                 u16* __restrict__ oh, u16* __restrict__ ol) {
  const long n = (long)B << 20;  // B * S * S, S*S = 2^20
  for (long i = blockIdx.x * (long)blockDim.x + threadIdx.x; i < n;
       i += gridDim.x * (long)blockDim.x) {
    const long b = i >> 20;
    const long rr = i & ((1L << 20) - 1);
    const float x = probs[(b * H + h) * (1L << 20) + rr];
    const u16 hh = f2bf_rn(x);
    oh[i] = hh;
    ol[i] = f2bf_rn(x - bf2f(hh));
  }
}

// out pair [C][R] = transpose of in [R][C], optional per-input-row divisor
__global__ __launch_bounds__(256) void transpose_split(
    const float* __restrict__ in, const float* __restrict__ divv,
    u16* __restrict__ oh, u16* __restrict__ ol, int R, int C) {
  __shared__ float t[32][33];
  const int bx = blockIdx.x * 32;  // C dim
  const int by = blockIdx.y * 32;  // R dim
  const int x = threadIdx.x & 31, y = threadIdx.x >> 5;
#pragma unroll
  for (int j = 0; j < 4; ++j) {
    const int rr = by + y + j * 8;
    float v = in[(long)rr * C + bx + x];
    if (divv) v /= divv[rr];
    t[y + j * 8][x] = v;
  }
  __syncthreads();
#pragma unroll
  for (int j = 0; j < 4; ++j) {
    const int c = bx + y + j * 8;
    const float v = t[x][y + j * 8];
    const u16 h = f2bf_rn(v);
    oh[(long)c * R + by + x] = h;
    ol[(long)c * R + by + x] = f2bf_rn(v - bf2f(h));
  }
}

__global__ void cvec_partial(const float* __restrict__ W_OV,
                             const float* __restrict__ ub1,
                             const float* __restrict__ ub2,
                             float* __restrict__ ctmp) {
  const int o = blockIdx.x * 256 + threadIdx.x;
  const int h = blockIdx.y;
  const float* W = W_OV + (long)h * D * D;
  float acc = 0.f;
  for (int i = 0; i < D; ++i)
    acc = fmaf(W[(long)i * D + o], ub1[i] + ub2[i], acc);
  ctmp[h * D + o] = acc;
}

__global__ void cvec_reduce(const float* __restrict__ ctmp, float* __restrict__ cvec) {
  const int o = blockIdx.x * blockDim.x + threadIdx.x;
  if (o < D) {
    float a = 0.f;
    for (int h = 0; h < H; ++h) a += ctmp[h * D + o];
    cvec[o] = a;
  }
}

__global__ __launch_bounds__(64) void bias_vec(
    const float* __restrict__ enc_w, const float* __restrict__ b_O,
    const float* __restrict__ b_dec, const float* __restrict__ enc_b,
    const float* __restrict__ cvec, float* __restrict__ bias0,
    float* __restrict__ evec) {
  const int f = blockIdx.x;
  const int l = threadIdx.x;
  float s1 = 0.f, s2 = 0.f;
  for (int o = l; o < D; o += 64) {
    const float w = enc_w[(long)f * D + o];
    s1 = fmaf(w, b_O[o] - b_dec[o], s1);
    s2 = fmaf(w, cvec[o], s2);
  }
  for (int off = 32; off > 0; off >>= 1) {
    s1 += __shfl_down(s1, off);
    s2 += __shfl_down(s2, off);
  }
  if (l == 0) { bias0[f] = s1 + enc_b[f]; evec[f] = s2; }
}

__global__ __launch_bounds__(256) void transpose_dw(const float* __restrict__ in,
                                                    float* __restrict__ out) {
  __shared__ float t[32][33];
  const int bx = blockIdx.x * 32;
  const int by = blockIdx.y * 32;
  const int x = threadIdx.x & 31, y = threadIdx.x >> 5;
#pragma unroll
  for (int j = 0; j < 4; ++j) {
    const int row = y + j * 8;
    t[row][x] = in[(long)(by + row) * F + bx + x];
  }
  __syncthreads();
#pragma unroll
  for (int j = 0; j < 4; ++j) {
    const int row = y + j * 8;
    out[(long)(bx + row) * D + by + x] = t[x][row];
  }
}

// top-64 of (bias0 + evec/ln + featP) per row, IN PLACE: read row, zero it,
// relu+scatter top-64 back; record (v,idx) for recon.
__global__ __launch_bounds__(256) void topk_fused(
    float* __restrict__ featP, const float* __restrict__ bias0,
    const float* __restrict__ evec, const float* __restrict__ ln,
    float* __restrict__ topv, int* __restrict__ topi) {
  const int row = blockIdx.x;  // b*S+s
  const float rln = 1.f / ln[row];
  float* p0 = featP + (long)row * F;
  __shared__ float vals[F];
  __shared__ float rv[256];
  __shared__ int ri[256];
  for (int j = threadIdx.x; j < F; j += 256)
    vals[j] = bias0[j] + evec[j] * rln + p0[j];
  __syncthreads();
  for (int j = threadIdx.x; j < F; j += 256) p0[j] = 0.f;
  __syncthreads();
  for (int it = 0; it < TOPK; ++it) {
    float best = -3.4e38f;
    int bi = F;
    for (int j = threadIdx.x; j < F; j += 256) {
      const float v = vals[j];
      if (v > best) { best = v; bi = j; }  // strict > keeps lowest index
    }
    rv[threadIdx.x] = best; ri[threadIdx.x] = bi;
    __syncthreads();
    for (int s2 = 128; s2 > 0; s2 >>= 1) {
      if (threadIdx.x < s2) {
        const float ov = rv[threadIdx.x + s2];
        const int oi = ri[threadIdx.x + s2];
        if (ov > rv[threadIdx.x] ||
            (ov == rv[threadIdx.x] && oi < ri[threadIdx.x])) {
          rv[threadIdx.x] = ov; ri[threadIdx.x] = oi;
        }
      }
      __syncthreads();
    }
    if (threadIdx.x == 0) {
      const int idx = ri[0];
      const float v = fmaxf(rv[0], 0.f);
      p0[idx] = v;
      topv[row * TOPK + it] = v;
      topi[row * TOPK + it] = idx;
      vals[idx] = -3.4e38f;
    }
    __syncthreads();
  }
}

__global__ __launch_bounds__(256) void recon_kernel(
    const float* __restrict__ topv, const int* __restrict__ topi,
    const float* __restrict__ dec_wT, const float* __restrict__ b_dec,
    float* __restrict__ recon) {
  const int row = blockIdx.x;
  __shared__ float sv[TOPK];
  __shared__ int si[TOPK];
  if (threadIdx.x < TOPK) {
    sv[threadIdx.x] = topv[row * TOPK + threadIdx.x];
    si[threadIdx.x] = topi[row * TOPK + threadIdx.x];
  }
  __syncthreads();
  const int d0 = threadIdx.x, d1 = threadIdx.x + 256;
  float a0 = b_dec[d0], a1 = b_dec[d1];
  for (int j = 0; j < TOPK; ++j) {
    const float v = sv[j];
    const float* wp = dec_wT + (long)si[j] * D;
    a0 = fmaf(v, wp[d0], a0);
    a1 = fmaf(v, wp[d1], a1);
  }
  recon[(long)row * D + d0] = a0;
  recon[(long)row * D + d1] = a1;
}

// ================= launch =================
extern "C" void kernel_launch(void* const* d_in, const int* in_sizes, int n_in,
                              void* d_out, int out_size, void* d_ws, size_t ws_size,
                              hipStream_t stream) {
  const float* resid = (const float*)d_in[0];
  const float* ln    = (const float*)d_in[1];
  const float* probs = (const float*)d_in[2];
  const float* W_OV  = (const float*)d_in[3];
  const float* b_O   = (const float*)d_in[4];
  const float* enc_w = (const float*)d_in[5];
  const float* enc_b = (const float*)d_in[6];
  const float* b_dec = (const float*)d_in[7];
  const float* dec_w = (const float*)d_in[8];
  const float* up_dec_[2]  = {(const float*)d_in[9], (const float*)d_in[13]};
  const float* up_bdec_[2] = {(const float*)d_in[10], (const float*)d_in[14]};
  const float* pf_[2]      = {(const float*)d_in[11], (const float*)d_in[15]};
  const float* mask_[2]    = {(const float*)d_in[12], (const float*)d_in[16]};

  float* out_feat  = (float*)d_out;   // doubles as the dense P accumulator
  float* out_recon = out_feat + (size_t)B * S * F;
  float* P = out_feat;

  constexpr int NALL = D + 2 * F;   // 6656 = 52*128
  constexpr int NB0  = D + F;       // 3584: B0 = [Eh | vw_u] columns
  // ---- workspace layout: 189.8 MB (< 191.9 MB proven in round 2) ----
  float* ws = (float*)d_ws;
  size_t o = 0;
  float* bias0 = ws + o; o += F;
  float* evec  = ws + o; o += F;
  float* cvec  = ws + o; o += D;
  float* ctmp  = ws + o; o += (size_t)H * D;
  float* topv  = ws + o; o += (size_t)B * S * TOPK;
  int*   topi  = (int*)(ws + o); o += (size_t)B * S * TOPK;
  u16* encwPh = (u16*)(ws + o); o += (size_t)F * D / 2;
  u16* encwPl = (u16*)(ws + o); o += (size_t)F * D / 2;
  u16* wovPh  = (u16*)(ws + o); o += (size_t)H * D * D / 2;
  u16* wovPl  = (u16*)(ws + o); o += (size_t)H * D * D / 2;
  u16* udTh   = (u16*)(ws + o); o += (size_t)2 * F * D / 2;       // [u][F][D]
  u16* udTl   = (u16*)(ws + o); o += (size_t)2 * F * D / 2;
  u16* Gallh  = (u16*)(ws + o); o += (size_t)B * NALL * S / 2;    // [b][6656][S]
  u16* Galll  = (u16*)(ws + o); o += (size_t)B * NALL * S / 2;
  u16* Phh    = (u16*)(ws + o); o += (size_t)B * S * S / 2;       // per-h probs
  u16* Phl    = (u16*)(ws + o); o += (size_t)B * S * S / 2;
  u16* B0h    = (u16*)(ws + o); o += (size_t)F * NB0 / 2;         // [d][3584]
  u16* B0l    = (u16*)(ws + o); o += (size_t)F * NB0 / 2;
  const size_t xoff = o;                                          // dec_wT alias
  u16* Xallh  = (u16*)(ws + o); o += (size_t)B * S * NALL / 2;    // [b][q][6656]
  u16* Xalll  = (u16*)(ws + o); o += (size_t)B * S * NALL / 2;
  float* dec_wT = ws + xoff;  // used only after h-loop (Xall dead by then)

  hipMemsetAsync(P, 0, sizeof(float) * (size_t)B * S * F, stream);

  // ---- operand prep ----
  split_pair<<<1024, 256, 0, stream>>>(enc_w, encwPh, encwPl, (long)F * D);
  split_pair<<<1024, 256, 0, stream>>>(W_OV, wovPh, wovPl, (long)H * D * D);
  for (int b = 0; b < B; ++b) {
    // Gall rows 0..511 = resid^T/ln
    transpose_split<<<dim3(D / 32, S / 32), 256, 0, stream>>>(
        resid + (size_t)b * S * D, ln + (size_t)b * S,
        Gallh + ((size_t)b * NALL + 0) * S, Galll + ((size_t)b * NALL + 0) * S,
        S, D);
    // Gall rows 512+u*3072 .. = pf_u^T/ln
    for (int u = 0; u < 2; ++u)
      transpose_split<<<dim3(F / 32, S / 32), 256, 0, stream>>>(
          pf_[u] + (size_t)b * S * F, ln + (size_t)b * S,
          Gallh + ((size_t)b * NALL + 512 + (size_t)u * F) * S,
          Galll + ((size_t)b * NALL + 512 + (size_t)u * F) * S, S, F);
  }
  for (int u = 0; u < 2; ++u)
    transpose_split<<<dim3(F / 32, D / 32), 256, 0, stream>>>(
        up_dec_[u], nullptr, udTh + (size_t)u * F * D, udTl + (size_t)u * F * D,
        D, F);
  cvec_partial<<<dim3(2, 8), 256, 0, stream>>>(W_OV, up_bdec_[0], up_bdec_[1], ctmp);
  cvec_reduce<<<2, 256, 0, stream>>>(ctmp, cvec);
  bias_vec<<<F, 64, 0, stream>>>(enc_w, b_O, b_dec, enc_b, cvec, bias0, evec);

  // ---- per-head pipeline ----
  for (int h = 0; h < H; ++h) {
    // probs[:,h] split pair (both b, one dispatch)
    split_pair_probs<<<2048, 256, 0, stream>>>(probs, h, Phh, Phl);
    // Eh[f,i] (3p) -> B0 cols 0..511 (ldc = 3584)
    gemm_split3<false, false, false, true><<<96, 256, 0, stream>>>(
        encwPh, encwPl, wovPh + (size_t)h * D * D, wovPl + (size_t)h * D * D,
        nullptr, B0h, B0l, nullptr, nullptr, 0,
        512, D, D, NB0, 4, 24, 1, 0L, 0L, 0L, 0L, 0L, 0L);
    // Xall[b][q][0:6656] = probs_h[b] @ Gall[b]^T (causal, 3p) -> pair
    gemm_split3<false, true, false, true><<<832, 256, 0, stream>>>(
        Phh, Phl, Gallh, Galll, nullptr, Xallh, Xalll, nullptr, nullptr, 0,
        S, S, S, NALL, NALL / 128, 8, 2,
        (long)S * S, 0L, (long)NALL * S, 0L, (long)S * NALL, 0L);

    for (int u = 0; u < 2; ++u) {
      // vw_u[d][n] = (Eh @ udT_u^T) * mask_u (3p) -> B0 cols 512..3583
      // A = Eh pair read from B0 cols 0..511 (lda = 3584); disjoint from write.
      gemm_split3<false, false, true, true><<<576, 256, 0, stream>>>(
          B0h, B0l, udTh + (size_t)u * F * D, udTl + (size_t)u * F * D,
          nullptr, B0h + 512, B0l + 512, mask_[u], nullptr, F,
          512, NB0, D, NB0, 24, 24, 1, 0L, 0L, 0L, 0L, 0L, 0L);
      if (u == 0) {
        // P[b] += Xall[:, 0:3584] @ B0^T   (3p, K=3584: Xact@Eh^T + Xu0@vw^T)
        gemm_split3<true, false, false, false><<<384, 256, 0, stream>>>(
            Xallh, Xalll, B0h, B0l, P, nullptr, nullptr, nullptr, nullptr, 0,
            NB0, NALL, NB0, F, 24, 8, 2,
            (long)S * NALL, 0L, 0L, 0L, (long)S * F, 0L);
      } else {
        // P[b] += Xall[:, 3584:6656] @ vw_u1^T  (3p, K=3072, ldb=3584)
        gemm_split3<true, false, false, false><<<384, 256, 0, stream>>>(
            Xallh + NB0, Xalll + NB0, B0h + 512, B0l + 512,
            P, nullptr, nullptr, nullptr, nullptr, 0,
            3072, NALL, NB0, F, 24, 8, 2,
            (long)S * NALL, 0L, 0L, 0L, (long)S * F, 0L);
      }
    }
  }

  // ---- tail: dec_w transpose (into dead Xall region), topk in-place, recon ----
  transpose_dw<<<dim3(F / 32, D / 32), 256, 0, stream>>>(dec_w, dec_wT);
  topk_fused<<<B * S, 256, 0, stream>>>(P, bias0, evec, ln, topv, topi);
  recon_kernel<<<B * S, 256, 0, stream>>>(topv, topi, dec_wT, b_dec, out_recon);
}

// Round 11
// 3867.021 us; speedup vs baseline: 1.2261x; 1.0958x over previous
//
#include <hip/hip_runtime.h>

constexpr int B = 2, S = 1024, D = 512, H = 8, F = 3072, TOPK = 64;

typedef unsigned short u16;
typedef unsigned int u32;
typedef __attribute__((ext_vector_type(8))) short bfrag;    // 8 bf16 (4 VGPR)
typedef __attribute__((ext_vector_type(4))) float f32x4;

__device__ __forceinline__ u16 f2bf_rn(float x) {
  u32 u = __float_as_uint(x);
  u32 r = (u + 0x7FFFu + ((u >> 16) & 1u)) >> 16;
  return (u16)r;
}
__device__ __forceinline__ float bf2f(u16 h) {
  return __uint_as_float(((u32)h) << 16);
}

#define GLOAD_LDS16(gp, lp)                                                   \
  __builtin_amdgcn_global_load_lds(                                           \
      (const __attribute__((address_space(1))) u32*)(gp),                     \
      (__attribute__((address_space(3))) u32*)(lp), 16, 0, 0)

// ---- stage one 128x32 bf16 tile (8KB) into LDS, granule-swizzled ----
// LDS slot s (16B granules): row = s>>2, slot sl = s&3 holds global k-granule
// sl ^ ((row>>1)&3). Write side linear (gload_lds); permutation applied on the
// per-lane GLOBAL source address (rule 21: both-sides involution).
__device__ __forceinline__ void stage_tile2(const u16* __restrict__ g, int r0,
                                            int ld, int k0, u16* lds,
                                            int w, int lane) {
#pragma unroll
  for (int p = 0; p < 2; ++p) {
    const int slot = w * 128 + p * 64 + lane;
    const int row = slot >> 2, sl = slot & 3;
    const int gr = sl ^ ((row >> 1) & 3);
    const u16* gp = g + (long)(r0 + row) * ld + k0 + gr * 8;
    u16* lp = lds + (w * 128 + p * 64) * 8;  // wave-uniform base; +lane*16B auto
    GLOAD_LDS16(gp, lp);
  }
}

// read fragment: lane group lg holds global k-granule lg of `row`
__device__ __forceinline__ bfrag frag_at(const u16* tile, int row, int lg) {
  const int idx = row * 32 + ((lg ^ ((row >> 1) & 3)) << 3);
  return *(const bfrag*)(tile + idx);
}

// ============ split-bf16 NT MFMA GEMM (round-7 core + rect XCD tiles) ======
// C[M,N] (+)= A[M,K] @ Bt[N,K]^T, operands as bf16 hi/lo pairs.
// 3-product AhBh+AhBl+AlBh, f32 MFMA accum — ALL paths (r6/r9 proved the
// top-k boundary gap is below 1p noise; precision stays at 3p, period).
// 128x128 block, BK=32, 4 waves (2x2 of 64x64). Double-buffered LDS (64KB),
// one __syncthreads per K-step, next stage issued before reads of current.
// XCD locality: bijective swizzle gives XCD i the contiguous sw chunk
// [i*q, (i+1)*q); when grq>0 that chunk is decoded as a grq x gcq RECTANGLE
// of (row-panel, col-panel) tiles instead of x-major rows — per-XCD operand
// footprint drops from (2 rows + all cols) to (grq + gcq) panels. Round-10
// counters: 306MB fetched vs 123MB ideal on accums = this pathology.
template<bool ACCUM, bool CAUSAL, bool MASK, bool OUTPAIR>
__global__ __launch_bounds__(256) void gemm_split3(
    const u16* __restrict__ Ah0, const u16* __restrict__ Al0,
    const u16* __restrict__ Bh0, const u16* __restrict__ Bl0,
    float* __restrict__ C, u16* __restrict__ Ch, u16* __restrict__ Cl,
    const float* __restrict__ mask0, const float* __restrict__ mask1, int ldm,
    int K, int lda, int ldb, int ldc, int gx, int gy, int NB, int grq, int gcq,
    long sAb, long sAh, long sBb, long sBh, long sCb, long sCh)
{
  __shared__ u16 smem[32768];  // 2 bufs x 4 tiles x 4096 u16 = 64 KB

  // bijective XCD swizzle (m204): XCD = blockIdx.x & 7 owns a contiguous
  // sw chunk of q = nwg/8 (all grids here are multiples of 8).
  const int nwg = gridDim.x;
  const int q = nwg >> 3, r = nwg & 7;
  const int xcd = blockIdx.x & 7, lid = blockIdx.x >> 3;
  const int sw = (xcd < r ? xcd * (q + 1) : r * (q + 1) + (xcd - r) * q) + lid;

  int z, by, bx;
  if (grq > 0) {
    // rectangle decode: rows_tot = NZ*gy, requirement rows_tot%grq==0,
    // gx%gcq==0; each rect is grq x gcq blocks, rects laid row-band-major.
    const int rcnt = grq * gcq;
    const int rect = sw / rcnt;
    const int wi = sw - rect * rcnt;
    const int rbr = wi / gcq, rbc = wi - rbr * gcq;
    const int cb = gx / gcq;             // rect columns per row band
    const int row = (rect / cb) * grq + rbr;
    const int col = (rect - (rect / cb) * cb) * gcq + rbc;
    z = row / gy; by = row - z * gy; bx = col;
  } else {
    const int gxy = gx * gy;
    z = sw / gxy;
    const int rem = sw - z * gxy;
    by = rem / gx; bx = rem - by * gx;
  }
  const int zb = z % NB, zh = z / NB;

  const u16* Ahp = Ah0 + zb * sAb + zh * sAh;
  const u16* Alp = Al0 + zb * sAb + zh * sAh;
  const u16* Bhp = Bh0 + zb * sBb + zh * sBh;
  const u16* Blp = Bl0 + zb * sBb + zh * sBh;
  const long coff = zb * sCb + zh * sCh;

  const int bm = by * 128, bn = bx * 128;
  const int tid = threadIdx.x;
  const int lane = tid & 63, w = tid >> 6;
  const int wr = w >> 1, wc = w & 1;
  const int lg = lane >> 4, lr = lane & 15;

  f32x4 acc[4][4];
#pragma unroll
  for (int i = 0; i < 4; ++i)
#pragma unroll
    for (int j = 0; j < 4; ++j) {
      acc[i][j][0] = 0.f; acc[i][j][1] = 0.f;
      acc[i][j][2] = 0.f; acc[i][j][3] = 0.f;
    }

  const int kmax = CAUSAL ? min(K, bm + 128) : K;
  const int nt = kmax >> 5;

#define STAGE(buf, k0)                                        \
  do {                                                        \
    u16* base_ = smem + (buf) * 16384;                        \
    stage_tile2(Ahp, bm, lda, (k0), base_,         w, lane);  \
    stage_tile2(Alp, bm, lda, (k0), base_ + 4096,  w, lane);  \
    stage_tile2(Bhp, bn, ldb, (k0), base_ + 8192,  w, lane);  \
    stage_tile2(Blp, bn, ldb, (k0), base_ + 12288, w, lane);  \
  } while (0)

  STAGE(0, 0);
  for (int t = 0; t < nt; ++t) {
    const int cur = t & 1;
    __syncthreads();                       // drains prior stage (vmcnt 0)
    if (t + 1 < nt) STAGE(cur ^ 1, (t + 1) << 5);  // overlaps with compute
    const u16* bufp = smem + cur * 16384;
    bfrag ah[4], al4[4], bh4[4], bl4[4];
#pragma unroll
    for (int i = 0; i < 4; ++i) {
      const int rowA = wr * 64 + i * 16 + lr;
      const int rowB = wc * 64 + i * 16 + lr;
      ah[i]  = frag_at(bufp,          rowA, lg);
      al4[i] = frag_at(bufp + 4096,   rowA, lg);
      bh4[i] = frag_at(bufp + 8192,   rowB, lg);
      bl4[i] = frag_at(bufp + 12288,  rowB, lg);
    }
#pragma unroll
    for (int i = 0; i < 4; ++i)
#pragma unroll
      for (int j = 0; j < 4; ++j) {
        acc[i][j] = __builtin_amdgcn_mfma_f32_16x16x32_bf16(ah[i],  bh4[j], acc[i][j], 0, 0, 0);
        acc[i][j] = __builtin_amdgcn_mfma_f32_16x16x32_bf16(ah[i],  bl4[j], acc[i][j], 0, 0, 0);
        acc[i][j] = __builtin_amdgcn_mfma_f32_16x16x32_bf16(al4[i], bh4[j], acc[i][j], 0, 0, 0);
      }
  }
#undef STAGE

  // epilogue: C/D layout col = lane&15, row = (lane>>4)*4 + reg
  const float* mp_ = MASK ? (zh ? mask1 : mask0) : nullptr;
#pragma unroll
  for (int i = 0; i < 4; ++i)
#pragma unroll
    for (int j = 0; j < 4; ++j)
#pragma unroll
      for (int rr = 0; rr < 4; ++rr) {
        const int row = bm + wr * 64 + i * 16 + lg * 4 + rr;
        const int col = bn + wc * 64 + j * 16 + lr;
        float v = acc[i][j][rr];
        if (MASK) v *= mp_[(long)row * ldm + col];
        const long ci = coff + (long)row * ldc + col;
        if (OUTPAIR) {
          const u16 h = f2bf_rn(v);
          Ch[ci] = h;
          Cl[ci] = f2bf_rn(v - bf2f(h));
        } else if (ACCUM) {
          C[ci] += v;
        } else {
          C[ci] = v;
        }
      }
}

// ================= small kernels =================
__global__ void split_pair(const float* __restrict__ in, u16* __restrict__ oh,
                           u16* __restrict__ ol, long n) {
  for (long i = blockIdx.x * (long)blockDim.x + threadIdx.x; i < n;
       i += gridDim.x * (long)blockDim.x) {
    const float x = in[i];
    const u16 h = f2bf_rn(x);
    oh[i] = h;
    ol[i] = f2bf_rn(x - bf2f(h));
  }
}

// probs[:, h] (both b) split into a contiguous [b][S][S] pair
__global__ void split_pair_probs(const float* __restrict__ probs, int h,
                                 u16* __restrict__ oh, u16* __restrict__ ol) {
  const long n = (long)B << 20;  // B * S * S, S*S = 2^20
  for (long i = blockIdx.x * (long)blockDim.x + threadIdx.x; i < n;
       i += gridDim.x * (long)blockDim.x) {
    const long b = i >> 20;
    const long rr = i & ((1L << 20) - 1);
    const float x = probs[(b * H + h) * (1L << 20) + rr];
    const u16 hh = f2bf_rn(x);
    oh[i] = hh;
    ol[i] = f2bf_rn(x - bf2f(hh));
  }
}

// out pair [C][R] = transpose of in [R][C], optional per-input-row divisor
__global__ __launch_bounds__(256) void transpose_split(
    const float* __restrict__ in, const float* __restrict__ divv,
    u16* __restrict__ oh, u16* __restrict__ ol, int R, int C) {
  __shared__ float t[32][33];
  const int bx = blockIdx.x * 32;  // C dim
  const int by = blockIdx.y * 32;  // R dim
  const int x = threadIdx.x & 31, y = threadIdx.x >> 5;
#pragma unroll
  for (int j = 0; j < 4; ++j) {
    const int rr = by + y + j * 8;
    float v = in[(long)rr * C + bx + x];
    if (divv) v /= divv[rr];
    t[y + j * 8][x] = v;
  }
  __syncthreads();
#pragma unroll
  for (int j = 0; j < 4; ++j) {
    const int c = bx + y + j * 8;
    const float v = t[x][y + j * 8];
    const u16 h = f2bf_rn(v);
    oh[(long)c * R + by + x] = h;
    ol[(long)c * R + by + x] = f2bf_rn(v - bf2f(h));
  }
}

__global__ void cvec_partial(const float* __restrict__ W_OV,
                             const float* __restrict__ ub1,
                             const float* __restrict__ ub2,
                             float* __restrict__ ctmp) {
  const int o = blockIdx.x * 256 + threadIdx.x;
  const int h = blockIdx.y;
  const float* W = W_OV + (long)h * D * D;
  float acc = 0.f;
  for (int i = 0; i < D; ++i)
    acc = fmaf(W[(long)i * D + o], ub1[i] + ub2[i], acc);
  ctmp[h * D + o] = acc;
}

__global__ void cvec_reduce(const float* __restrict__ ctmp, float* __restrict__ cvec) {
  const int o = blockIdx.x * blockDim.x + threadIdx.x;
  if (o < D) {
    float a = 0.f;
    for (int h = 0; h < H; ++h) a += ctmp[h * D + o];
    cvec[o] = a;
  }
}

__global__ __launch_bounds__(64) void bias_vec(
    const float* __restrict__ enc_w, const float* __restrict__ b_O,
    const float* __restrict__ b_dec, const float* __restrict__ enc_b,
    const float* __restrict__ cvec, float* __restrict__ bias0,
    float* __restrict__ evec) {
  const int f = blockIdx.x;
  const int l = threadIdx.x;
  float s1 = 0.f, s2 = 0.f;
  for (int o = l; o < D; o += 64) {
    const float w = enc_w[(long)f * D + o];
    s1 = fmaf(w, b_O[o] - b_dec[o], s1);
    s2 = fmaf(w, cvec[o], s2);
  }
  for (int off = 32; off > 0; off >>= 1) {
    s1 += __shfl_down(s1, off);
    s2 += __shfl_down(s2, off);
  }
  if (l == 0) { bias0[f] = s1 + enc_b[f]; evec[f] = s2; }
}

__global__ __launch_bounds__(256) void transpose_dw(const float* __restrict__ in,
                                                    float* __restrict__ out) {
  __shared__ float t[32][33];
  const int bx = blockIdx.x * 32;
  const int by = blockIdx.y * 32;
  const int x = threadIdx.x & 31, y = threadIdx.x >> 5;
#pragma unroll
  for (int j = 0; j < 4; ++j) {
    const int row = y + j * 8;
    t[row][x] = in[(long)(by + row) * F + bx + x];
  }
  __syncthreads();
#pragma unroll
  for (int j = 0; j < 4; ++j) {
    const int row = y + j * 8;
    out[(long)(bx + row) * D + by + x] = t[x][row];
  }
}

// top-64 of (bias0 + evec/ln + featP) per row, IN PLACE: read row, zero it,
// relu+scatter top-64 back; record (v,idx) for recon.
__global__ __launch_bounds__(256) void topk_fused(
    float* __restrict__ featP, const float* __restrict__ bias0,
    const float* __restrict__ evec, const float* __restrict__ ln,
    float* __restrict__ topv, int* __restrict__ topi) {
  const int row = blockIdx.x;  // b*S+s
  const float rln = 1.f / ln[row];
  float* p0 = featP + (long)row * F;
  __shared__ float vals[F];
  __shared__ float rv[256];
  __shared__ int ri[256];
  for (int j = threadIdx.x; j < F; j += 256)
    vals[j] = bias0[j] + evec[j] * rln + p0[j];
  __syncthreads();
  for (int j = threadIdx.x; j < F; j += 256) p0[j] = 0.f;
  __syncthreads();
  for (int it = 0; it < TOPK; ++it) {
    float best = -3.4e38f;
    int bi = F;
    for (int j = threadIdx.x; j < F; j += 256) {
      const float v = vals[j];
      if (v > best) { best = v; bi = j; }  // strict > keeps lowest index
    }
    rv[threadIdx.x] = best; ri[threadIdx.x] = bi;
    __syncthreads();
    for (int s2 = 128; s2 > 0; s2 >>= 1) {
      if (threadIdx.x < s2) {
        const float ov = rv[threadIdx.x + s2];
        const int oi = ri[threadIdx.x + s2];
        if (ov > rv[threadIdx.x] ||
            (ov == rv[threadIdx.x] && oi < ri[threadIdx.x])) {
          rv[threadIdx.x] = ov; ri[threadIdx.x] = oi;
        }
      }
      __syncthreads();
    }
    if (threadIdx.x == 0) {
      const int idx = ri[0];
      const float v = fmaxf(rv[0], 0.f);
      p0[idx] = v;
      topv[row * TOPK + it] = v;
      topi[row * TOPK + it] = idx;
      vals[idx] = -3.4e38f;
    }
    __syncthreads();
  }
}

__global__ __launch_bounds__(256) void recon_kernel(
    const float* __restrict__ topv, const int* __restrict__ topi,
    const float* __restrict__ dec_wT, const float* __restrict__ b_dec,
    float* __restrict__ recon) {
  const int row = blockIdx.x;
  __shared__ float sv[TOPK];
  __shared__ int si[TOPK];
  if (threadIdx.x < TOPK) {
    sv[threadIdx.x] = topv[row * TOPK + threadIdx.x];
    si[threadIdx.x] = topi[row * TOPK + threadIdx.x];
  }
  __syncthreads();
  const int d0 = threadIdx.x, d1 = threadIdx.x + 256;
  float a0 = b_dec[d0], a1 = b_dec[d1];
  for (int j = 0; j < TOPK; ++j) {
    const float v = sv[j];
    const float* wp = dec_wT + (long)si[j] * D;
    a0 = fmaf(v, wp[d0], a0);
    a1 = fmaf(v, wp[d1], a1);
  }
  recon[(long)row * D + d0] = a0;
  recon[(long)row * D + d1] = a1;
}

// ================= launch =================
extern "C" void kernel_launch(void* const* d_in, const int* in_sizes, int n_in,
                              void* d_out, int out_size, void* d_ws, size_t ws_size,
                              hipStream_t stream) {
  const float* resid = (const float*)d_in[0];
  const float* ln    = (const float*)d_in[1];
  const float* probs = (const float*)d_in[2];
  const float* W_OV  = (const float*)d_in[3];
  const float* b_O   = (const float*)d_in[4];
  const float* enc_w = (const float*)d_in[5];
  const float* enc_b = (const float*)d_in[6];
  const float* b_dec = (const float*)d_in[7];
  const float* dec_w = (const float*)d_in[8];
  const float* up_dec_[2]  = {(const float*)d_in[9], (const float*)d_in[13]};
  const float* up_bdec_[2] = {(const float*)d_in[10], (const float*)d_in[14]};
  const float* pf_[2]      = {(const float*)d_in[11], (const float*)d_in[15]};
  const float* mask_[2]    = {(const float*)d_in[12], (const float*)d_in[16]};

  float* out_feat  = (float*)d_out;   // doubles as the dense P accumulator
  float* out_recon = out_feat + (size_t)B * S * F;
  float* P = out_feat;

  constexpr int NALL = D + 2 * F;   // 6656 = 52*128
  constexpr int NB0  = D + F;       // 3584: B0 = [Eh | vw_u] columns
  // ---- workspace layout: 189.8 MB (< 191.9 MB proven in round 2) ----
  float* ws = (float*)d_ws;
  size_t o = 0;
  float* bias0 = ws + o; o += F;
  float* evec  = ws + o; o += F;
  float* cvec  = ws + o; o += D;
  float* ctmp  = ws + o; o += (size_t)H * D;
  float* topv  = ws + o; o += (size_t)B * S * TOPK;
  int*   topi  = (int*)(ws + o); o += (size_t)B * S * TOPK;
  u16* encwPh = (u16*)(ws + o); o += (size_t)F * D / 2;
  u16* encwPl = (u16*)(ws + o); o += (size_t)F * D / 2;
  u16* wovPh  = (u16*)(ws + o); o += (size_t)H * D * D / 2;
  u16* wovPl  = (u16*)(ws + o); o += (size_t)H * D * D / 2;
  u16* udTh   = (u16*)(ws + o); o += (size_t)2 * F * D / 2;       // [u][F][D]
  u16* udTl   = (u16*)(ws + o); o += (size_t)2 * F * D / 2;
  u16* Gallh  = (u16*)(ws + o); o += (size_t)B * NALL * S / 2;    // [b][6656][S]
  u16* Galll  = (u16*)(ws + o); o += (size_t)B * NALL * S / 2;
  u16* Phh    = (u16*)(ws + o); o += (size_t)B * S * S / 2;       // per-h probs
  u16* Phl    = (u16*)(ws + o); o += (size_t)B * S * S / 2;
  u16* B0h    = (u16*)(ws + o); o += (size_t)F * NB0 / 2;         // [d][3584]
  u16* B0l    = (u16*)(ws + o); o += (size_t)F * NB0 / 2;
  const size_t xoff = o;                                          // dec_wT alias
  u16* Xallh  = (u16*)(ws + o); o += (size_t)B * S * NALL / 2;    // [b][q][6656]
  u16* Xalll  = (u16*)(ws + o); o += (size_t)B * S * NALL / 2;
  float* dec_wT = ws + xoff;  // used only after h-loop (Xall dead by then)

  // NOTE: no P memset — the h==0,u==0 accumulate is launched with
  // ACCUM=false and overwrites every element of P deterministically.

  // ---- operand prep ----
  split_pair<<<1024, 256, 0, stream>>>(enc_w, encwPh, encwPl, (long)F * D);
  split_pair<<<1024, 256, 0, stream>>>(W_OV, wovPh, wovPl, (long)H * D * D);
  for (int b = 0; b < B; ++b) {
    // Gall rows 0..511 = resid^T/ln
    transpose_split<<<dim3(D / 32, S / 32), 256, 0, stream>>>(
        resid + (size_t)b * S * D, ln + (size_t)b * S,
        Gallh + ((size_t)b * NALL + 0) * S, Galll + ((size_t)b * NALL + 0) * S,
        S, D);
    // Gall rows 512+u*3072 .. = pf_u^T/ln
    for (int u = 0; u < 2; ++u)
      transpose_split<<<dim3(F / 32, S / 32), 256, 0, stream>>>(
          pf_[u] + (size_t)b * S * F, ln + (size_t)b * S,
          Gallh + ((size_t)b * NALL + 512 + (size_t)u * F) * S,
          Galll + ((size_t)b * NALL + 512 + (size_t)u * F) * S, S, F);
  }
  for (int u = 0; u < 2; ++u)
    transpose_split<<<dim3(F / 32, D / 32), 256, 0, stream>>>(
        up_dec_[u], nullptr, udTh + (size_t)u * F * D, udTl + (size_t)u * F * D,
        D, F);
  cvec_partial<<<dim3(2, 8), 256, 0, stream>>>(W_OV, up_bdec_[0], up_bdec_[1], ctmp);
  cvec_reduce<<<2, 256, 0, stream>>>(ctmp, cvec);
  bias_vec<<<F, 64, 0, stream>>>(enc_w, b_O, b_dec, enc_b, cvec, bias0, evec);

  // ---- per-head pipeline ----
  for (int h = 0; h < H; ++h) {
    // probs[:,h] split pair (both b, one dispatch)
    split_pair_probs<<<2048, 256, 0, stream>>>(probs, h, Phh, Phl);
    // Eh[f,i] (3p) -> B0 cols 0..511 (ldc = 3584); rects 6x2 (rows 24, cols 4)
    gemm_split3<false, false, false, true><<<96, 256, 0, stream>>>(
        encwPh, encwPl, wovPh + (size_t)h * D * D, wovPl + (size_t)h * D * D,
        nullptr, B0h, B0l, nullptr, nullptr, 0,
        512, D, D, NB0, 4, 24, 1, 6, 2, 0L, 0L, 0L, 0L, 0L, 0L);
    // Xall[b][q][0:6656] = probs_h[b] @ Gall[b]^T (causal, 3p) -> pair
    // rects 8x13 (rows 16, cols 52): per-XCD Gall footprint 52 -> 13 panels
    gemm_split3<false, true, false, true><<<832, 256, 0, stream>>>(
        Phh, Phl, Gallh, Galll, nullptr, Xallh, Xalll, nullptr, nullptr, 0,
        S, S, S, NALL, NALL / 128, 8, 2, 8, 13,
        (long)S * S, 0L, (long)NALL * S, 0L, (long)S * NALL, 0L);

    for (int u = 0; u < 2; ++u) {
      // vw_u[d][n] = (Eh @ udT_u^T) * mask_u (3p) -> B0 cols 512..3583
      // A = Eh pair read from B0 cols 0..511 (lda = 3584); rects 12x6
      gemm_split3<false, false, true, true><<<576, 256, 0, stream>>>(
          B0h, B0l, udTh + (size_t)u * F * D, udTl + (size_t)u * F * D,
          nullptr, B0h + 512, B0l + 512, mask_[u], nullptr, F,
          512, NB0, D, NB0, 24, 24, 1, 12, 6, 0L, 0L, 0L, 0L, 0L, 0L);
      if (u == 0) {
        // P[b] (+)= Xall[:, 0:3584] @ B0^T (3p, K=3584); h==0: pure store.
        // rects 8x6 (rows 16, cols 24): per-XCD B0 footprint 24 -> 6 panels
        if (h == 0) {
          gemm_split3<false, false, false, false><<<384, 256, 0, stream>>>(
              Xallh, Xalll, B0h, B0l, P, nullptr, nullptr, nullptr, nullptr, 0,
              NB0, NALL, NB0, F, 24, 8, 2, 8, 6,
              (long)S * NALL, 0L, 0L, 0L, (long)S * F, 0L);
        } else {
          gemm_split3<true, false, false, false><<<384, 256, 0, stream>>>(
              Xallh, Xalll, B0h, B0l, P, nullptr, nullptr, nullptr, nullptr, 0,
              NB0, NALL, NB0, F, 24, 8, 2, 8, 6,
              (long)S * NALL, 0L, 0L, 0L, (long)S * F, 0L);
        }
      } else {
        // P[b] += Xall[:, 3584:6656] @ vw_u1^T  (3p, K=3072, ldb=3584)
        gemm_split3<true, false, false, false><<<384, 256, 0, stream>>>(
            Xallh + NB0, Xalll + NB0, B0h + 512, B0l + 512,
            P, nullptr, nullptr, nullptr, nullptr, 0,
            3072, NALL, NB0, F, 24, 8, 2, 8, 6,
            (long)S * NALL, 0L, 0L, 0L, (long)S * F, 0L);
      }
    }
  }

  // ---- tail: dec_w transpose (into dead Xall region), topk in-place, recon ----
  transpose_dw<<<dim3(F / 32, D / 32), 256, 0, stream>>>(dec_w, dec_wT);
  topk_fused<<<B * S, 256, 0, stream>>>(P, bias0, evec, ln, topv, topi);
  recon_kernel<<<B * S, 256, 0, stream>>>(topv, topi, dec_wT, b_dec, out_recon);
}

// Round 12
// 3652.438 us; speedup vs baseline: 1.2981x; 1.0588x over previous
//
#include <hip/hip_runtime.h>

constexpr int B = 2, S = 1024, D = 512, H = 8, F = 3072, TOPK = 64;

typedef unsigned short u16;
typedef unsigned int u32;
typedef __attribute__((ext_vector_type(8))) short bfrag;    // 8 bf16 (4 VGPR)
typedef __attribute__((ext_vector_type(4))) float f32x4;

__device__ __forceinline__ u16 f2bf_rn(float x) {
  u32 u = __float_as_uint(x);
  u32 r = (u + 0x7FFFu + ((u >> 16) & 1u)) >> 16;
  return (u16)r;
}
__device__ __forceinline__ float bf2f(u16 h) {
  return __uint_as_float(((u32)h) << 16);
}

#define GLOAD_LDS16(gp, lp)                                                   \
  __builtin_amdgcn_global_load_lds(                                           \
      (const __attribute__((address_space(1))) u32*)(gp),                     \
      (__attribute__((address_space(3))) u32*)(lp), 16, 0, 0)

// ---- stage one ROWSx32 bf16 tile into LDS, granule-swizzled ----
// LDS slot s (16B granules): row = s>>2, slot sl = s&3 holds global k-granule
// sl ^ ((row>>1)&3). Write side linear (gload_lds); permutation applied on the
// per-lane GLOBAL source address (rule 21). ROWS=128: 512 granules, 2 full
// passes. ROWS=96: 384 granules, pass 1 only waves 0-1 (wave-uniform guard).
// Slot assignment p*256 + w*64 + lane is a bijection; LDS image identical to
// the round-11 layout.
template<int ROWS>
__device__ __forceinline__ void stage_tileR(const u16* __restrict__ g, int r0,
                                            int ld, int k0, u16* lds,
                                            int w, int lane) {
#pragma unroll
  for (int p = 0; p < 2; ++p) {
    const int slot = p * 256 + w * 64 + lane;
    if (ROWS == 128 || slot < ROWS * 4) {
      const int row = slot >> 2, sl = slot & 3;
      const int gr = sl ^ ((row >> 1) & 3);
      const u16* gp = g + (long)(r0 + row) * ld + k0 + gr * 8;
      u16* lp = lds + (p * 256 + w * 64) * 8;  // wave-uniform; +lane*16B auto
      GLOAD_LDS16(gp, lp);
    }
  }
}

// read fragment: lane group lg holds global k-granule lg of `row`
__device__ __forceinline__ bfrag frag_at(const u16* tile, int row, int lg) {
  const int idx = row * 32 + ((lg ^ ((row >> 1) & 3)) << 3);
  return *(const bfrag*)(tile + idx);
}

// ============ split-bf16 NT MFMA GEMM (r7 core + rect XCD + BN param) ======
// C[M,N] (+)= A[M,K] @ Bt[N,K]^T, operands as bf16 hi/lo pairs.
// 3-product AhBh+AhBl+AlBh, f32 MFMA accum — ALL paths (r6/r9 proved the
// top-k boundary gap is below 1p noise; precision stays at 3p, period).
// Block tile 128 x BN, BN in {128, 96}. 4 waves (2x2 of 64 x BN/2), BK=32,
// double-buffered LDS (64KB / 56KB -> 2 blocks/CU), one __syncthreads per
// K-step, next stage issued before reads of current.
// BN=96 exists to make grids EXACT multiples of 256 CUs (r11 counters:
// 384-block accums = 1.5 blocks/CU imbalance was the binding inefficiency).
// XCD locality: rect decode as round 11 (grq x gcq rectangles per XCD).
template<int BN, bool ACCUM, bool CAUSAL, bool MASK, bool OUTPAIR>
__global__ __launch_bounds__(256) void gemm_split3(
    const u16* __restrict__ Ah0, const u16* __restrict__ Al0,
    const u16* __restrict__ Bh0, const u16* __restrict__ Bl0,
    float* __restrict__ C, u16* __restrict__ Ch, u16* __restrict__ Cl,
    const float* __restrict__ mask0, const float* __restrict__ mask1, int ldm,
    int K, int lda, int ldb, int ldc, int gx, int gy, int NB, int grq, int gcq,
    long sAb, long sAh, long sBb, long sBh, long sCb, long sCh)
{
  constexpr int BGR = BN * 32;                  // B-tile u16 count
  constexpr int STRIDE = 8192 + 2 * BGR;        // u16 per stage
  constexpr int NF = BN / 32;                   // B frags per wave (4 or 3)
  __shared__ u16 smem[2 * STRIDE];

  // bijective XCD swizzle (m204): XCD = blockIdx.x & 7 owns a contiguous
  // sw chunk of q = nwg/8 (all grids here are multiples of 8).
  const int nwg = gridDim.x;
  const int q = nwg >> 3, r = nwg & 7;
  const int xcd = blockIdx.x & 7, lid = blockIdx.x >> 3;
  const int sw = (xcd < r ? xcd * (q + 1) : r * (q + 1) + (xcd - r) * q) + lid;

  int z, by, bx;
  if (grq > 0) {
    const int rcnt = grq * gcq;
    const int rect = sw / rcnt;
    const int wi = sw - rect * rcnt;
    const int rbr = wi / gcq, rbc = wi - rbr * gcq;
    const int cb = gx / gcq;             // rect columns per row band
    const int row = (rect / cb) * grq + rbr;
    const int col = (rect - (rect / cb) * cb) * gcq + rbc;
    z = row / gy; by = row - z * gy; bx = col;
  } else {
    const int gxy = gx * gy;
    z = sw / gxy;
    const int rem = sw - z * gxy;
    by = rem / gx; bx = rem - by * gx;
  }
  const int zb = z % NB, zh = z / NB;

  const u16* Ahp = Ah0 + zb * sAb + zh * sAh;
  const u16* Alp = Al0 + zb * sAb + zh * sAh;
  const u16* Bhp = Bh0 + zb * sBb + zh * sBh;
  const u16* Blp = Bl0 + zb * sBb + zh * sBh;
  const long coff = zb * sCb + zh * sCh;

  const int bm = by * 128, bn = bx * BN;
  const int tid = threadIdx.x;
  const int lane = tid & 63, w = tid >> 6;
  const int wr = w >> 1, wc = w & 1;
  const int lg = lane >> 4, lr = lane & 15;

  f32x4 acc[4][NF];
#pragma unroll
  for (int i = 0; i < 4; ++i)
#pragma unroll
    for (int j = 0; j < NF; ++j) {
      acc[i][j][0] = 0.f; acc[i][j][1] = 0.f;
      acc[i][j][2] = 0.f; acc[i][j][3] = 0.f;
    }

  const int kmax = CAUSAL ? min(K, bm + 128) : K;
  const int nt = kmax >> 5;

#define STAGE(buf, k0)                                                  \
  do {                                                                  \
    u16* base_ = smem + (buf) * STRIDE;                                 \
    stage_tileR<128>(Ahp, bm, lda, (k0), base_,             w, lane);   \
    stage_tileR<128>(Alp, bm, lda, (k0), base_ + 4096,      w, lane);   \
    stage_tileR<BN> (Bhp, bn, ldb, (k0), base_ + 8192,      w, lane);   \
    stage_tileR<BN> (Blp, bn, ldb, (k0), base_ + 8192 + BGR, w, lane);  \
  } while (0)

  STAGE(0, 0);
  for (int t = 0; t < nt; ++t) {
    const int cur = t & 1;
    __syncthreads();                       // drains prior stage (vmcnt 0)
    if (t + 1 < nt) STAGE(cur ^ 1, (t + 1) << 5);  // overlaps with compute
    const u16* bufp = smem + cur * STRIDE;
    bfrag ah[4], al4[4], bh4[NF], bl4[NF];
#pragma unroll
    for (int j = 0; j < NF; ++j) {
      const int rowB = wc * (BN / 2) + j * 16 + lr;
      bh4[j] = frag_at(bufp + 8192,       rowB, lg);
      bl4[j] = frag_at(bufp + 8192 + BGR, rowB, lg);
    }
#pragma unroll
    for (int i = 0; i < 4; ++i) {
      const int rowA = wr * 64 + i * 16 + lr;
      ah[i]  = frag_at(bufp,        rowA, lg);
      al4[i] = frag_at(bufp + 4096, rowA, lg);
    }
#pragma unroll
    for (int i = 0; i < 4; ++i)
#pragma unroll
      for (int j = 0; j < NF; ++j) {
        acc[i][j] = __builtin_amdgcn_mfma_f32_16x16x32_bf16(ah[i],  bh4[j], acc[i][j], 0, 0, 0);
        acc[i][j] = __builtin_amdgcn_mfma_f32_16x16x32_bf16(ah[i],  bl4[j], acc[i][j], 0, 0, 0);
        acc[i][j] = __builtin_amdgcn_mfma_f32_16x16x32_bf16(al4[i], bh4[j], acc[i][j], 0, 0, 0);
      }
  }
#undef STAGE

  // epilogue: C/D layout col = lane&15, row = (lane>>4)*4 + reg
  const float* mp_ = MASK ? (zh ? mask1 : mask0) : nullptr;
#pragma unroll
  for (int i = 0; i < 4; ++i)
#pragma unroll
    for (int j = 0; j < NF; ++j)
#pragma unroll
      for (int rr = 0; rr < 4; ++rr) {
        const int row = bm + wr * 64 + i * 16 + lg * 4 + rr;
        const int col = bn + wc * (BN / 2) + j * 16 + lr;
        float v = acc[i][j][rr];
        if (MASK) v *= mp_[(long)row * ldm + col];
        const long ci = coff + (long)row * ldc + col;
        if (OUTPAIR) {
          const u16 h = f2bf_rn(v);
          Ch[ci] = h;
          Cl[ci] = f2bf_rn(v - bf2f(h));
        } else if (ACCUM) {
          C[ci] += v;
        } else {
          C[ci] = v;
        }
      }
}

// ================= small kernels =================
__global__ void split_pair(const float* __restrict__ in, u16* __restrict__ oh,
                           u16* __restrict__ ol, long n) {
  for (long i = blockIdx.x * (long)blockDim.x + threadIdx.x; i < n;
       i += gridDim.x * (long)blockDim.x) {
    const float x = in[i];
    const u16 h = f2bf_rn(x);
    oh[i] = h;
    ol[i] = f2bf_rn(x - bf2f(h));
  }
}

// probs[:, h] (both b) split into a contiguous [b][S][S] pair
__global__ void split_pair_probs(const float* __restrict__ probs, int h,
                                 u16* __restrict__ oh, u16* __restrict__ ol) {
  const long n = (long)B << 20;  // B * S * S, S*S = 2^20
  for (long i = blockIdx.x * (long)blockDim.x + threadIdx.x; i < n;
       i += gridDim.x * (long)blockDim.x) {
    const long b = i >> 20;
    const long rr = i & ((1L << 20) - 1);
    const float x = probs[(b * H + h) * (1L << 20) + rr];
    const u16 hh = f2bf_rn(x);
    oh[i] = hh;
    ol[i] = f2bf_rn(x - bf2f(hh));
  }
}

// out pair [C][R] = transpose of in [R][C], optional per-input-row divisor
__global__ __launch_bounds__(256) void transpose_split(
    const float* __restrict__ in, const float* __restrict__ divv,
    u16* __restrict__ oh, u16* __restrict__ ol, int R, int C) {
  __shared__ float t[32][33];
  const int bx = blockIdx.x * 32;  // C dim
  const int by = blockIdx.y * 32;  // R dim
  const int x = threadIdx.x & 31, y = threadIdx.x >> 5;
#pragma unroll
  for (int j = 0; j < 4; ++j) {
    const int rr = by + y + j * 8;
    float v = in[(long)rr * C + bx + x];
    if (divv) v /= divv[rr];
    t[y + j * 8][x] = v;
  }
  __syncthreads();
#pragma unroll
  for (int j = 0; j < 4; ++j) {
    const int c = bx + y + j * 8;
    const float v = t[x][y + j * 8];
    const u16 h = f2bf_rn(v);
    oh[(long)c * R + by + x] = h;
    ol[(long)c * R + by + x] = f2bf_rn(v - bf2f(h));
  }
}

__global__ void cvec_partial(const float* __restrict__ W_OV,
                             const float* __restrict__ ub1,
                             const float* __restrict__ ub2,
                             float* __restrict__ ctmp) {
  const int o = blockIdx.x * 256 + threadIdx.x;
  const int h = blockIdx.y;
  const float* W = W_OV + (long)h * D * D;
  float acc = 0.f;
  for (int i = 0; i < D; ++i)
    acc = fmaf(W[(long)i * D + o], ub1[i] + ub2[i], acc);
  ctmp[h * D + o] = acc;
}

__global__ void cvec_reduce(const float* __restrict__ ctmp, float* __restrict__ cvec) {
  const int o = blockIdx.x * blockDim.x + threadIdx.x;
  if (o < D) {
    float a = 0.f;
    for (int h = 0; h < H; ++h) a += ctmp[h * D + o];
    cvec[o] = a;
  }
}

__global__ __launch_bounds__(64) void bias_vec(
    const float* __restrict__ enc_w, const float* __restrict__ b_O,
    const float* __restrict__ b_dec, const float* __restrict__ enc_b,
    const float* __restrict__ cvec, float* __restrict__ bias0,
    float* __restrict__ evec) {
  const int f = blockIdx.x;
  const int l = threadIdx.x;
  float s1 = 0.f, s2 = 0.f;
  for (int o = l; o < D; o += 64) {
    const float w = enc_w[(long)f * D + o];
    s1 = fmaf(w, b_O[o] - b_dec[o], s1);
    s2 = fmaf(w, cvec[o], s2);
  }
  for (int off = 32; off > 0; off >>= 1) {
    s1 += __shfl_down(s1, off);
    s2 += __shfl_down(s2, off);
  }
  if (l == 0) { bias0[f] = s1 + enc_b[f]; evec[f] = s2; }
}

__global__ __launch_bounds__(256) void transpose_dw(const float* __restrict__ in,
                                                    float* __restrict__ out) {
  __shared__ float t[32][33];
  const int bx = blockIdx.x * 32;
  const int by = blockIdx.y * 32;
  const int x = threadIdx.x & 31, y = threadIdx.x >> 5;
#pragma unroll
  for (int j = 0; j < 4; ++j) {
    const int row = y + j * 8;
    t[row][x] = in[(long)(by + row) * F + bx + x];
  }
  __syncthreads();
#pragma unroll
  for (int j = 0; j < 4; ++j) {
    const int row = y + j * 8;
    out[(long)(bx + row) * D + by + x] = t[x][row];
  }
}

// top-64 of (bias0 + evec/ln + featP) per row, IN PLACE: read row, zero it,
// relu+scatter top-64 back; record (v,idx) for recon.
__global__ __launch_bounds__(256) void topk_fused(
    float* __restrict__ featP, const float* __restrict__ bias0,
    const float* __restrict__ evec, const float* __restrict__ ln,
    float* __restrict__ topv, int* __restrict__ topi) {
  const int row = blockIdx.x;  // b*S+s
  const float rln = 1.f / ln[row];
  float* p0 = featP + (long)row * F;
  __shared__ float vals[F];
  __shared__ float rv[256];
  __shared__ int ri[256];
  for (int j = threadIdx.x; j < F; j += 256)
    vals[j] = bias0[j] + evec[j] * rln + p0[j];
  __syncthreads();
  for (int j = threadIdx.x; j < F; j += 256) p0[j] = 0.f;
  __syncthreads();
  for (int it = 0; it < TOPK; ++it) {
    float best = -3.4e38f;
    int bi = F;
    for (int j = threadIdx.x; j < F; j += 256) {
      const float v = vals[j];
      if (v > best) { best = v; bi = j; }  // strict > keeps lowest index
    }
    rv[threadIdx.x] = best; ri[threadIdx.x] = bi;
    __syncthreads();
    for (int s2 = 128; s2 > 0; s2 >>= 1) {
      if (threadIdx.x < s2) {
        const float ov = rv[threadIdx.x + s2];
        const int oi = ri[threadIdx.x + s2];
        if (ov > rv[threadIdx.x] ||
            (ov == rv[threadIdx.x] && oi < ri[threadIdx.x])) {
          rv[threadIdx.x] = ov; ri[threadIdx.x] = oi;
        }
      }
      __syncthreads();
    }
    if (threadIdx.x == 0) {
      const int idx = ri[0];
      const float v = fmaxf(rv[0], 0.f);
      p0[idx] = v;
      topv[row * TOPK + it] = v;
      topi[row * TOPK + it] = idx;
      vals[idx] = -3.4e38f;
    }
    __syncthreads();
  }
}

__global__ __launch_bounds__(256) void recon_kernel(
    const float* __restrict__ topv, const int* __restrict__ topi,
    const float* __restrict__ dec_wT, const float* __restrict__ b_dec,
    float* __restrict__ recon) {
  const int row = blockIdx.x;
  __shared__ float sv[TOPK];
  __shared__ int si[TOPK];
  if (threadIdx.x < TOPK) {
    sv[threadIdx.x] = topv[row * TOPK + threadIdx.x];
    si[threadIdx.x] = topi[row * TOPK + threadIdx.x];
  }
  __syncthreads();
  const int d0 = threadIdx.x, d1 = threadIdx.x + 256;
  float a0 = b_dec[d0], a1 = b_dec[d1];
  for (int j = 0; j < TOPK; ++j) {
    const float v = sv[j];
    const float* wp = dec_wT + (long)si[j] * D;
    a0 = fmaf(v, wp[d0], a0);
    a1 = fmaf(v, wp[d1], a1);
  }
  recon[(long)row * D + d0] = a0;
  recon[(long)row * D + d1] = a1;
}

// ================= launch =================
extern "C" void kernel_launch(void* const* d_in, const int* in_sizes, int n_in,
                              void* d_out, int out_size, void* d_ws, size_t ws_size,
                              hipStream_t stream) {
  const float* resid = (const float*)d_in[0];
  const float* ln    = (const float*)d_in[1];
  const float* probs = (const float*)d_in[2];
  const float* W_OV  = (const float*)d_in[3];
  const float* b_O   = (const float*)d_in[4];
  const float* enc_w = (const float*)d_in[5];
  const float* enc_b = (const float*)d_in[6];
  const float* b_dec = (const float*)d_in[7];
  const float* dec_w = (const float*)d_in[8];
  const float* up_dec_[2]  = {(const float*)d_in[9], (const float*)d_in[13]};
  const float* up_bdec_[2] = {(const float*)d_in[10], (const float*)d_in[14]};
  const float* pf_[2]      = {(const float*)d_in[11], (const float*)d_in[15]};
  const float* mask_[2]    = {(const float*)d_in[12], (const float*)d_in[16]};

  float* out_feat  = (float*)d_out;   // doubles as the dense P accumulator
  float* out_recon = out_feat + (size_t)B * S * F;
  float* P = out_feat;

  constexpr int NALL = D + 2 * F;   // 6656 = 52*128
  constexpr int NB0  = D + F;       // 3584: B0 = [Eh | vw_u] columns
  // ---- workspace layout: 189.8 MB (< 191.9 MB proven in round 2) ----
  float* ws = (float*)d_ws;
  size_t o = 0;
  float* bias0 = ws + o; o += F;
  float* evec  = ws + o; o += F;
  float* cvec  = ws + o; o += D;
  float* ctmp  = ws + o; o += (size_t)H * D;
  float* topv  = ws + o; o += (size_t)B * S * TOPK;
  int*   topi  = (int*)(ws + o); o += (size_t)B * S * TOPK;
  u16* encwPh = (u16*)(ws + o); o += (size_t)F * D / 2;
  u16* encwPl = (u16*)(ws + o); o += (size_t)F * D / 2;
  u16* wovPh  = (u16*)(ws + o); o += (size_t)H * D * D / 2;
  u16* wovPl  = (u16*)(ws + o); o += (size_t)H * D * D / 2;
  u16* udTh   = (u16*)(ws + o); o += (size_t)2 * F * D / 2;       // [u][F][D]
  u16* udTl   = (u16*)(ws + o); o += (size_t)2 * F * D / 2;
  u16* Gallh  = (u16*)(ws + o); o += (size_t)B * NALL * S / 2;    // [b][6656][S]
  u16* Galll  = (u16*)(ws + o); o += (size_t)B * NALL * S / 2;
  u16* Phh    = (u16*)(ws + o); o += (size_t)B * S * S / 2;       // per-h probs
  u16* Phl    = (u16*)(ws + o); o += (size_t)B * S * S / 2;
  u16* B0h    = (u16*)(ws + o); o += (size_t)F * NB0 / 2;         // [d][3584]
  u16* B0l    = (u16*)(ws + o); o += (size_t)F * NB0 / 2;
  const size_t xoff = o;                                          // dec_wT alias
  u16* Xallh  = (u16*)(ws + o); o += (size_t)B * S * NALL / 2;    // [b][q][6656]
  u16* Xalll  = (u16*)(ws + o); o += (size_t)B * S * NALL / 2;
  float* dec_wT = ws + xoff;  // used only after h-loop (Xall dead by then)

  // NOTE: no P memset — the h==0,u==0 accumulate is launched with
  // ACCUM=false and overwrites every element of P deterministically.

  // ---- operand prep ----
  split_pair<<<1024, 256, 0, stream>>>(enc_w, encwPh, encwPl, (long)F * D);
  split_pair<<<1024, 256, 0, stream>>>(W_OV, wovPh, wovPl, (long)H * D * D);
  for (int b = 0; b < B; ++b) {
    // Gall rows 0..511 = resid^T/ln
    transpose_split<<<dim3(D / 32, S / 32), 256, 0, stream>>>(
        resid + (size_t)b * S * D, ln + (size_t)b * S,
        Gallh + ((size_t)b * NALL + 0) * S, Galll + ((size_t)b * NALL + 0) * S,
        S, D);
    // Gall rows 512+u*3072 .. = pf_u^T/ln
    for (int u = 0; u < 2; ++u)
      transpose_split<<<dim3(F / 32, S / 32), 256, 0, stream>>>(
          pf_[u] + (size_t)b * S * F, ln + (size_t)b * S,
          Gallh + ((size_t)b * NALL + 512 + (size_t)u * F) * S,
          Galll + ((size_t)b * NALL + 512 + (size_t)u * F) * S, S, F);
  }
  for (int u = 0; u < 2; ++u)
    transpose_split<<<dim3(F / 32, D / 32), 256, 0, stream>>>(
        up_dec_[u], nullptr, udTh + (size_t)u * F * D, udTl + (size_t)u * F * D,
        D, F);
  cvec_partial<<<dim3(2, 8), 256, 0, stream>>>(W_OV, up_bdec_[0], up_bdec_[1], ctmp);
  cvec_reduce<<<2, 256, 0, stream>>>(ctmp, cvec);
  bias_vec<<<F, 64, 0, stream>>>(enc_w, b_O, b_dec, enc_b, cvec, bias0, evec);

  // ---- per-head pipeline ----
  for (int h = 0; h < H; ++h) {
    // probs[:,h] split pair (both b, one dispatch)
    split_pair_probs<<<2048, 256, 0, stream>>>(probs, h, Phh, Phl);
    // Eh[f,i] (3p) -> B0 cols 0..511 (ldc = 3584); rects 6x2 (rows 24, cols 4)
    gemm_split3<128, false, false, false, true><<<96, 256, 0, stream>>>(
        encwPh, encwPl, wovPh + (size_t)h * D * D, wovPl + (size_t)h * D * D,
        nullptr, B0h, B0l, nullptr, nullptr, 0,
        512, D, D, NB0, 4, 24, 1, 6, 2, 0L, 0L, 0L, 0L, 0L, 0L);
    // Xall[b][q][0:6656] = probs_h[b] @ Gall[b]^T (causal, 3p) -> pair
    // rects 8x13 (rows 16, cols 52)
    gemm_split3<128, false, true, false, true><<<832, 256, 0, stream>>>(
        Phh, Phl, Gallh, Galll, nullptr, Xallh, Xalll, nullptr, nullptr, 0,
        S, S, S, NALL, NALL / 128, 8, 2, 8, 13,
        (long)S * S, 0L, (long)NALL * S, 0L, (long)S * NALL, 0L);

    for (int u = 0; u < 2; ++u) {
      // vw_u[d][n] = (Eh @ udT_u^T) * mask_u (3p) -> B0 cols 512..3583
      // BN=96: grid 24x32 = 768 = exactly 3 blocks/CU; rects 12x8
      gemm_split3<96, false, false, true, true><<<768, 256, 0, stream>>>(
          B0h, B0l, udTh + (size_t)u * F * D, udTl + (size_t)u * F * D,
          nullptr, B0h + 512, B0l + 512, mask_[u], nullptr, F,
          512, NB0, D, NB0, 32, 24, 1, 12, 8, 0L, 0L, 0L, 0L, 0L, 0L);
      if (u == 0) {
        // P[b] (+)= Xall[:, 0:3584] @ B0^T (3p, K=3584); h==0: pure store.
        // BN=96: grid 16x32 = 512 = exactly 2 blocks/CU; rects 8x8
        if (h == 0) {
          gemm_split3<96, false, false, false, false><<<512, 256, 0, stream>>>(
              Xallh, Xalll, B0h, B0l, P, nullptr, nullptr, nullptr, nullptr, 0,
              NB0, NALL, NB0, F, 32, 8, 2, 8, 8,
              (long)S * NALL, 0L, 0L, 0L, (long)S * F, 0L);
        } else {
          gemm_split3<96, true, false, false, false><<<512, 256, 0, stream>>>(
              Xallh, Xalll, B0h, B0l, P, nullptr, nullptr, nullptr, nullptr, 0,
              NB0, NALL, NB0, F, 32, 8, 2, 8, 8,
              (long)S * NALL, 0L, 0L, 0L, (long)S * F, 0L);
        }
      } else {
        // P[b] += Xall[:, 3584:6656] @ vw_u1^T  (3p, K=3072, ldb=3584)
        gemm_split3<96, true, false, false, false><<<512, 256, 0, stream>>>(
            Xallh + NB0, Xalll + NB0, B0h + 512, B0l + 512,
            P, nullptr, nullptr, nullptr, nullptr, 0,
            3072, NALL, NB0, F, 32, 8, 2, 8, 8,
            (long)S * NALL, 0L, 0L, 0L, (long)S * F, 0L);
      }
    }
  }

  // ---- tail: dec_w transpose (into dead Xall region), topk in-place, recon ----
  transpose_dw<<<dim3(F / 32, D / 32), 256, 0, stream>>>(dec_w, dec_wT);
  topk_fused<<<B * S, 256, 0, stream>>>(P, bias0, evec, ln, topv, topi);
  recon_kernel<<<B * S, 256, 0, stream>>>(topv, topi, dec_wT, b_dec, out_recon);
}

// Round 13
// 3592.875 us; speedup vs baseline: 1.3197x; 1.0166x over previous
//
#include <hip/hip_runtime.h>

constexpr int B = 2, S = 1024, D = 512, H = 8, F = 3072, TOPK = 64;

typedef unsigned short u16;
typedef unsigned int u32;
typedef __attribute__((ext_vector_type(8))) short bfrag;    // 8 bf16 (4 VGPR)
typedef __attribute__((ext_vector_type(4))) float f32x4;

__device__ __forceinline__ u16 f2bf_rn(float x) {
  u32 u = __float_as_uint(x);
  u32 r = (u + 0x7FFFu + ((u >> 16) & 1u)) >> 16;
  return (u16)r;
}
__device__ __forceinline__ float bf2f(u16 h) {
  return __uint_as_float(((u32)h) << 16);
}

#define GLOAD_LDS16(gp, lp)                                                   \
  __builtin_amdgcn_global_load_lds(                                           \
      (const __attribute__((address_space(1))) u32*)(gp),                     \
      (__attribute__((address_space(3))) u32*)(lp), 16, 0, 0)

// ---- stage one ROWSx32 bf16 tile into LDS, granule-swizzled ----
// LDS slot s (16B granules): row = s>>2, slot sl = s&3 holds global k-granule
// sl ^ ((row>>1)&3). Write side linear (gload_lds); permutation applied on the
// per-lane GLOBAL source address (rule 21). ROWS=128: 512 granules, 2 full
// passes. ROWS=96: 384 granules, pass 1 only waves 0-1 (wave-uniform guard).
template<int ROWS>
__device__ __forceinline__ void stage_tileR(const u16* __restrict__ g, int r0,
                                            int ld, int k0, u16* lds,
                                            int w, int lane) {
#pragma unroll
  for (int p = 0; p < 2; ++p) {
    const int slot = p * 256 + w * 64 + lane;
    if (ROWS == 128 || slot < ROWS * 4) {
      const int row = slot >> 2, sl = slot & 3;
      const int gr = sl ^ ((row >> 1) & 3);
      const u16* gp = g + (long)(r0 + row) * ld + k0 + gr * 8;
      u16* lp = lds + (p * 256 + w * 64) * 8;  // wave-uniform; +lane*16B auto
      GLOAD_LDS16(gp, lp);
    }
  }
}

// read fragment: lane group lg holds global k-granule lg of `row`
__device__ __forceinline__ bfrag frag_at(const u16* tile, int row, int lg) {
  const int idx = row * 32 + ((lg ^ ((row >> 1) & 3)) << 3);
  return *(const bfrag*)(tile + idx);
}

// ============ split-bf16 NT MFMA GEMM (r7 core + rect XCD + BN param) ======
// C[M,N] (+)= A[M,K] @ Bt[N,K]^T, operands as bf16 hi/lo pairs.
// 3-product AhBh+AhBl+AlBh, f32 MFMA accum — ALL paths (r6/r9 proved the
// top-k boundary gap is below 1p noise; precision stays at 3p, period).
// Block tile 128 x BN, BN in {128, 96}. 4 waves (2x2 of 64 x BN/2), BK=32,
// double-buffered LDS (64KB / 56KB -> 2 blocks/CU), one __syncthreads per
// K-step, next stage issued before reads of current.
// XCD locality: rect decode as round 11 (grq x gcq rectangles per XCD).
// CAUSAL heavy-first: by is flipped (gy-1-by) so the longest blocks
// (kmax = bm+128 largest) dispatch FIRST — the fractional last scheduling
// round gets the lightest blocks, shortening the causal tail. Pure
// bijective remap; numerics bit-identical.
template<int BN, bool ACCUM, bool CAUSAL, bool MASK, bool OUTPAIR>
__global__ __launch_bounds__(256) void gemm_split3(
    const u16* __restrict__ Ah0, const u16* __restrict__ Al0,
    const u16* __restrict__ Bh0, const u16* __restrict__ Bl0,
    float* __restrict__ C, u16* __restrict__ Ch, u16* __restrict__ Cl,
    const float* __restrict__ mask0, const float* __restrict__ mask1, int ldm,
    int K, int lda, int ldb, int ldc, int gx, int gy, int NB, int grq, int gcq,
    long sAb, long sAh, long sBb, long sBh, long sCb, long sCh)
{
  constexpr int BGR = BN * 32;                  // B-tile u16 count
  constexpr int STRIDE = 8192 + 2 * BGR;        // u16 per stage
  constexpr int NF = BN / 32;                   // B frags per wave (4 or 3)
  __shared__ u16 smem[2 * STRIDE];

  // bijective XCD swizzle (m204): XCD = blockIdx.x & 7 owns a contiguous
  // sw chunk of q = nwg/8 (all grids here are multiples of 8).
  const int nwg = gridDim.x;
  const int q = nwg >> 3, r = nwg & 7;
  const int xcd = blockIdx.x & 7, lid = blockIdx.x >> 3;
  const int sw = (xcd < r ? xcd * (q + 1) : r * (q + 1) + (xcd - r) * q) + lid;

  int z, by, bx;
  if (grq > 0) {
    const int rcnt = grq * gcq;
    const int rect = sw / rcnt;
    const int wi = sw - rect * rcnt;
    const int rbr = wi / gcq, rbc = wi - rbr * gcq;
    const int cb = gx / gcq;             // rect columns per row band
    const int row = (rect / cb) * grq + rbr;
    const int col = (rect - (rect / cb) * cb) * gcq + rbc;
    z = row / gy; by = row - z * gy; bx = col;
  } else {
    const int gxy = gx * gy;
    z = sw / gxy;
    const int rem = sw - z * gxy;
    by = rem / gx; bx = rem - by * gx;
  }
  if (CAUSAL) by = gy - 1 - by;          // heavy-first dispatch order
  const int zb = z % NB, zh = z / NB;

  const u16* Ahp = Ah0 + zb * sAb + zh * sAh;
  const u16* Alp = Al0 + zb * sAb + zh * sAh;
  const u16* Bhp = Bh0 + zb * sBb + zh * sBh;
  const u16* Blp = Bl0 + zb * sBb + zh * sBh;
  const long coff = zb * sCb + zh * sCh;

  const int bm = by * 128, bn = bx * BN;
  const int tid = threadIdx.x;
  const int lane = tid & 63, w = tid >> 6;
  const int wr = w >> 1, wc = w & 1;
  const int lg = lane >> 4, lr = lane & 15;

  f32x4 acc[4][NF];
#pragma unroll
  for (int i = 0; i < 4; ++i)
#pragma unroll
    for (int j = 0; j < NF; ++j) {
      acc[i][j][0] = 0.f; acc[i][j][1] = 0.f;
      acc[i][j][2] = 0.f; acc[i][j][3] = 0.f;
    }

  const int kmax = CAUSAL ? min(K, bm + 128) : K;
  const int nt = kmax >> 5;

#define STAGE(buf, k0)                                                  \
  do {                                                                  \
    u16* base_ = smem + (buf) * STRIDE;                                 \
    stage_tileR<128>(Ahp, bm, lda, (k0), base_,             w, lane);   \
    stage_tileR<128>(Alp, bm, lda, (k0), base_ + 4096,      w, lane);   \
    stage_tileR<BN> (Bhp, bn, ldb, (k0), base_ + 8192,      w, lane);   \
    stage_tileR<BN> (Blp, bn, ldb, (k0), base_ + 8192 + BGR, w, lane);  \
  } while (0)

  STAGE(0, 0);
  for (int t = 0; t < nt; ++t) {
    const int cur = t & 1;
    __syncthreads();                       // drains prior stage (vmcnt 0)
    if (t + 1 < nt) STAGE(cur ^ 1, (t + 1) << 5);  // overlaps with compute
    const u16* bufp = smem + cur * STRIDE;
    bfrag ah[4], al4[4], bh4[NF], bl4[NF];
#pragma unroll
    for (int j = 0; j < NF; ++j) {
      const int rowB = wc * (BN / 2) + j * 16 + lr;
      bh4[j] = frag_at(bufp + 8192,       rowB, lg);
      bl4[j] = frag_at(bufp + 8192 + BGR, rowB, lg);
    }
#pragma unroll
    for (int i = 0; i < 4; ++i) {
      const int rowA = wr * 64 + i * 16 + lr;
      ah[i]  = frag_at(bufp,        rowA, lg);
      al4[i] = frag_at(bufp + 4096, rowA, lg);
    }
#pragma unroll
    for (int i = 0; i < 4; ++i)
#pragma unroll
      for (int j = 0; j < NF; ++j) {
        acc[i][j] = __builtin_amdgcn_mfma_f32_16x16x32_bf16(ah[i],  bh4[j], acc[i][j], 0, 0, 0);
        acc[i][j] = __builtin_amdgcn_mfma_f32_16x16x32_bf16(ah[i],  bl4[j], acc[i][j], 0, 0, 0);
        acc[i][j] = __builtin_amdgcn_mfma_f32_16x16x32_bf16(al4[i], bh4[j], acc[i][j], 0, 0, 0);
      }
  }
#undef STAGE

  // epilogue: C/D layout col = lane&15, row = (lane>>4)*4 + reg
  const float* mp_ = MASK ? (zh ? mask1 : mask0) : nullptr;
#pragma unroll
  for (int i = 0; i < 4; ++i)
#pragma unroll
    for (int j = 0; j < NF; ++j)
#pragma unroll
      for (int rr = 0; rr < 4; ++rr) {
        const int row = bm + wr * 64 + i * 16 + lg * 4 + rr;
        const int col = bn + wc * (BN / 2) + j * 16 + lr;
        float v = acc[i][j][rr];
        if (MASK) v *= mp_[(long)row * ldm + col];
        const long ci = coff + (long)row * ldc + col;
        if (OUTPAIR) {
          const u16 h = f2bf_rn(v);
          Ch[ci] = h;
          Cl[ci] = f2bf_rn(v - bf2f(h));
        } else if (ACCUM) {
          C[ci] += v;
        } else {
          C[ci] = v;
        }
      }
}

// ================= small kernels =================
__global__ void split_pair(const float* __restrict__ in, u16* __restrict__ oh,
                           u16* __restrict__ ol, long n) {
  for (long i = blockIdx.x * (long)blockDim.x + threadIdx.x; i < n;
       i += gridDim.x * (long)blockDim.x) {
    const float x = in[i];
    const u16 h = f2bf_rn(x);
    oh[i] = h;
    ol[i] = f2bf_rn(x - bf2f(h));
  }
}

// probs[:, h] (both b) split into a contiguous [b][S][S] pair
__global__ void split_pair_probs(const float* __restrict__ probs, int h,
                                 u16* __restrict__ oh, u16* __restrict__ ol) {
  const long n = (long)B << 20;  // B * S * S, S*S = 2^20
  for (long i = blockIdx.x * (long)blockDim.x + threadIdx.x; i < n;
       i += gridDim.x * (long)blockDim.x) {
    const long b = i >> 20;
    const long rr = i & ((1L << 20) - 1);
    const float x = probs[(b * H + h) * (1L << 20) + rr];
    const u16 hh = f2bf_rn(x);
    oh[i] = hh;
    ol[i] = f2bf_rn(x - bf2f(hh));
  }
}

// out pair [C][R] = transpose of in [R][C], optional per-input-row divisor
__global__ __launch_bounds__(256) void transpose_split(
    const float* __restrict__ in, const float* __restrict__ divv,
    u16* __restrict__ oh, u16* __restrict__ ol, int R, int C) {
  __shared__ float t[32][33];
  const int bx = blockIdx.x * 32;  // C dim
  const int by = blockIdx.y * 32;  // R dim
  const int x = threadIdx.x & 31, y = threadIdx.x >> 5;
#pragma unroll
  for (int j = 0; j < 4; ++j) {
    const int rr = by + y + j * 8;
    float v = in[(long)rr * C + bx + x];
    if (divv) v /= divv[rr];
    t[y + j * 8][x] = v;
  }
  __syncthreads();
#pragma unroll
  for (int j = 0; j < 4; ++j) {
    const int c = bx + y + j * 8;
    const float v = t[x][y + j * 8];
    const u16 h = f2bf_rn(v);
    oh[(long)c * R + by + x] = h;
    ol[(long)c * R + by + x] = f2bf_rn(v - bf2f(h));
  }
}

__global__ void cvec_partial(const float* __restrict__ W_OV,
                             const float* __restrict__ ub1,
                             const float* __restrict__ ub2,
                             float* __restrict__ ctmp) {
  const int o = blockIdx.x * 256 + threadIdx.x;
  const int h = blockIdx.y;
  const float* W = W_OV + (long)h * D * D;
  float acc = 0.f;
  for (int i = 0; i < D; ++i)
    acc = fmaf(W[(long)i * D + o], ub1[i] + ub2[i], acc);
  ctmp[h * D + o] = acc;
}

__global__ void cvec_reduce(const float* __restrict__ ctmp, float* __restrict__ cvec) {
  const int o = blockIdx.x * blockDim.x + threadIdx.x;
  if (o < D) {
    float a = 0.f;
    for (int h = 0; h < H; ++h) a += ctmp[h * D + o];
    cvec[o] = a;
  }
}

__global__ __launch_bounds__(64) void bias_vec(
    const float* __restrict__ enc_w, const float* __restrict__ b_O,
    const float* __restrict__ b_dec, const float* __restrict__ enc_b,
    const float* __restrict__ cvec, float* __restrict__ bias0,
    float* __restrict__ evec) {
  const int f = blockIdx.x;
  const int l = threadIdx.x;
  float s1 = 0.f, s2 = 0.f;
  for (int o = l; o < D; o += 64) {
    const float w = enc_w[(long)f * D + o];
    s1 = fmaf(w, b_O[o] - b_dec[o], s1);
    s2 = fmaf(w, cvec[o], s2);
  }
  for (int off = 32; off > 0; off >>= 1) {
    s1 += __shfl_down(s1, off);
    s2 += __shfl_down(s2, off);
  }
  if (l == 0) { bias0[f] = s1 + enc_b[f]; evec[f] = s2; }
}

__global__ __launch_bounds__(256) void transpose_dw(const float* __restrict__ in,
                                                    float* __restrict__ out) {
  __shared__ float t[32][33];
  const int bx = blockIdx.x * 32;
  const int by = blockIdx.y * 32;
  const int x = threadIdx.x & 31, y = threadIdx.x >> 5;
#pragma unroll
  for (int j = 0; j < 4; ++j) {
    const int row = y + j * 8;
    t[row][x] = in[(long)(by + row) * F + bx + x];
  }
  __syncthreads();
#pragma unroll
  for (int j = 0; j < 4; ++j) {
    const int row = y + j * 8;
    out[(long)(bx + row) * D + by + x] = t[x][row];
  }
}

// top-64 of (bias0 + evec/ln + featP) per row, IN PLACE: read row, zero it,
// relu+scatter top-64 back; record (v,idx) for recon.
__global__ __launch_bounds__(256) void topk_fused(
    float* __restrict__ featP, const float* __restrict__ bias0,
    const float* __restrict__ evec, const float* __restrict__ ln,
    float* __restrict__ topv, int* __restrict__ topi) {
  const int row = blockIdx.x;  // b*S+s
  const float rln = 1.f / ln[row];
  float* p0 = featP + (long)row * F;
  __shared__ float vals[F];
  __shared__ float rv[256];
  __shared__ int ri[256];
  for (int j = threadIdx.x; j < F; j += 256)
    vals[j] = bias0[j] + evec[j] * rln + p0[j];
  __syncthreads();
  for (int j = threadIdx.x; j < F; j += 256) p0[j] = 0.f;
  __syncthreads();
  for (int it = 0; it < TOPK; ++it) {
    float best = -3.4e38f;
    int bi = F;
    for (int j = threadIdx.x; j < F; j += 256) {
      const float v = vals[j];
      if (v > best) { best = v; bi = j; }  // strict > keeps lowest index
    }
    rv[threadIdx.x] = best; ri[threadIdx.x] = bi;
    __syncthreads();
    for (int s2 = 128; s2 > 0; s2 >>= 1) {
      if (threadIdx.x < s2) {
        const float ov = rv[threadIdx.x + s2];
        const int oi = ri[threadIdx.x + s2];
        if (ov > rv[threadIdx.x] ||
            (ov == rv[threadIdx.x] && oi < ri[threadIdx.x])) {
          rv[threadIdx.x] = ov; ri[threadIdx.x] = oi;
        }
      }
      __syncthreads();
    }
    if (threadIdx.x == 0) {
      const int idx = ri[0];
      const float v = fmaxf(rv[0], 0.f);
      p0[idx] = v;
      topv[row * TOPK + it] = v;
      topi[row * TOPK + it] = idx;
      vals[idx] = -3.4e38f;
    }
    __syncthreads();
  }
}

__global__ __launch_bounds__(256) void recon_kernel(
    const float* __restrict__ topv, const int* __restrict__ topi,
    const float* __restrict__ dec_wT, const float* __restrict__ b_dec,
    float* __restrict__ recon) {
  const int row = blockIdx.x;
  __shared__ float sv[TOPK];
  __shared__ int si[TOPK];
  if (threadIdx.x < TOPK) {
    sv[threadIdx.x] = topv[row * TOPK + threadIdx.x];
    si[threadIdx.x] = topi[row * TOPK + threadIdx.x];
  }
  __syncthreads();
  const int d0 = threadIdx.x, d1 = threadIdx.x + 256;
  float a0 = b_dec[d0], a1 = b_dec[d1];
  for (int j = 0; j < TOPK; ++j) {
    const float v = sv[j];
    const float* wp = dec_wT + (long)si[j] * D;
    a0 = fmaf(v, wp[d0], a0);
    a1 = fmaf(v, wp[d1], a1);
  }
  recon[(long)row * D + d0] = a0;
  recon[(long)row * D + d1] = a1;
}

// ================= launch =================
extern "C" void kernel_launch(void* const* d_in, const int* in_sizes, int n_in,
                              void* d_out, int out_size, void* d_ws, size_t ws_size,
                              hipStream_t stream) {
  const float* resid = (const float*)d_in[0];
  const float* ln    = (const float*)d_in[1];
  const float* probs = (const float*)d_in[2];
  const float* W_OV  = (const float*)d_in[3];
  const float* b_O   = (const float*)d_in[4];
  const float* enc_w = (const float*)d_in[5];
  const float* enc_b = (const float*)d_in[6];
  const float* b_dec = (const float*)d_in[7];
  const float* dec_w = (const float*)d_in[8];
  const float* up_dec_[2]  = {(const float*)d_in[9], (const float*)d_in[13]};
  const float* up_bdec_[2] = {(const float*)d_in[10], (const float*)d_in[14]};
  const float* pf_[2]      = {(const float*)d_in[11], (const float*)d_in[15]};
  const float* mask_[2]    = {(const float*)d_in[12], (const float*)d_in[16]};

  float* out_feat  = (float*)d_out;   // doubles as the dense P accumulator
  float* out_recon = out_feat + (size_t)B * S * F;
  float* P = out_feat;

  constexpr int NALL = D + 2 * F;   // 6656 = 52*128
  constexpr int NB0  = D + F;       // 3584: B0 = [Eh | vw_u] columns
  // ---- workspace layout: 189.8 MB (< 191.9 MB proven in round 2) ----
  float* ws = (float*)d_ws;
  size_t o = 0;
  float* bias0 = ws + o; o += F;
  float* evec  = ws + o; o += F;
  float* cvec  = ws + o; o += D;
  float* ctmp  = ws + o; o += (size_t)H * D;
  float* topv  = ws + o; o += (size_t)B * S * TOPK;
  int*   topi  = (int*)(ws + o); o += (size_t)B * S * TOPK;
  u16* encwPh = (u16*)(ws + o); o += (size_t)F * D / 2;
  u16* encwPl = (u16*)(ws + o); o += (size_t)F * D / 2;
  u16* wovPh  = (u16*)(ws + o); o += (size_t)H * D * D / 2;
  u16* wovPl  = (u16*)(ws + o); o += (size_t)H * D * D / 2;
  u16* udTh   = (u16*)(ws + o); o += (size_t)2 * F * D / 2;       // [u][F][D]
  u16* udTl   = (u16*)(ws + o); o += (size_t)2 * F * D / 2;
  u16* Gallh  = (u16*)(ws + o); o += (size_t)B * NALL * S / 2;    // [b][6656][S]
  u16* Galll  = (u16*)(ws + o); o += (size_t)B * NALL * S / 2;
  u16* Phh    = (u16*)(ws + o); o += (size_t)B * S * S / 2;       // per-h probs
  u16* Phl    = (u16*)(ws + o); o += (size_t)B * S * S / 2;
  u16* B0h    = (u16*)(ws + o); o += (size_t)F * NB0 / 2;         // [d][3584]
  u16* B0l    = (u16*)(ws + o); o += (size_t)F * NB0 / 2;
  const size_t xoff = o;                                          // dec_wT alias
  u16* Xallh  = (u16*)(ws + o); o += (size_t)B * S * NALL / 2;    // [b][q][6656]
  u16* Xalll  = (u16*)(ws + o); o += (size_t)B * S * NALL / 2;
  float* dec_wT = ws + xoff;  // used only after h-loop (Xall dead by then)

  // NOTE: no P memset — the h==0,u==0 accumulate is launched with
  // ACCUM=false and overwrites every element of P deterministically.

  // ---- operand prep ----
  split_pair<<<1024, 256, 0, stream>>>(enc_w, encwPh, encwPl, (long)F * D);
  split_pair<<<1024, 256, 0, stream>>>(W_OV, wovPh, wovPl, (long)H * D * D);
  for (int b = 0; b < B; ++b) {
    // Gall rows 0..511 = resid^T/ln
    transpose_split<<<dim3(D / 32, S / 32), 256, 0, stream>>>(
        resid + (size_t)b * S * D, ln + (size_t)b * S,
        Gallh + ((size_t)b * NALL + 0) * S, Galll + ((size_t)b * NALL + 0) * S,
        S, D);
    // Gall rows 512+u*3072 .. = pf_u^T/ln
    for (int u = 0; u < 2; ++u)
      transpose_split<<<dim3(F / 32, S / 32), 256, 0, stream>>>(
          pf_[u] + (size_t)b * S * F, ln + (size_t)b * S,
          Gallh + ((size_t)b * NALL + 512 + (size_t)u * F) * S,
          Galll + ((size_t)b * NALL + 512 + (size_t)u * F) * S, S, F);
  }
  for (int u = 0; u < 2; ++u)
    transpose_split<<<dim3(F / 32, D / 32), 256, 0, stream>>>(
        up_dec_[u], nullptr, udTh + (size_t)u * F * D, udTl + (size_t)u * F * D,
        D, F);
  cvec_partial<<<dim3(2, 8), 256, 0, stream>>>(W_OV, up_bdec_[0], up_bdec_[1], ctmp);
  cvec_reduce<<<2, 256, 0, stream>>>(ctmp, cvec);
  bias_vec<<<F, 64, 0, stream>>>(enc_w, b_O, b_dec, enc_b, cvec, bias0, evec);

  // ---- per-head pipeline ----
  for (int h = 0; h < H; ++h) {
    // probs[:,h] split pair (both b, one dispatch)
    split_pair_probs<<<2048, 256, 0, stream>>>(probs, h, Phh, Phl);
    // Eh[f,i] (3p) -> B0 cols 0..511 (ldc = 3584); rects 6x2 (rows 24, cols 4)
    gemm_split3<128, false, false, false, true><<<96, 256, 0, stream>>>(
        encwPh, encwPl, wovPh + (size_t)h * D * D, wovPl + (size_t)h * D * D,
        nullptr, B0h, B0l, nullptr, nullptr, 0,
        512, D, D, NB0, 4, 24, 1, 6, 2, 0L, 0L, 0L, 0L, 0L, 0L);
    // Xall[b][q][0:6656] = probs_h[b] @ Gall[b]^T (causal, 3p, heavy-first)
    // rects 8x13 (rows 16, cols 52)
    gemm_split3<128, false, true, false, true><<<832, 256, 0, stream>>>(
        Phh, Phl, Gallh, Galll, nullptr, Xallh, Xalll, nullptr, nullptr, 0,
        S, S, S, NALL, NALL / 128, 8, 2, 8, 13,
        (long)S * S, 0L, (long)NALL * S, 0L, (long)S * NALL, 0L);

    for (int u = 0; u < 2; ++u) {
      // vw_u[d][n] = (Eh @ udT_u^T) * mask_u (3p) -> B0 cols 512..3583
      // BN=96: grid 24x32 = 768 = exactly 3 blocks/CU; rects 12x8
      gemm_split3<96, false, false, true, true><<<768, 256, 0, stream>>>(
          B0h, B0l, udTh + (size_t)u * F * D, udTl + (size_t)u * F * D,
          nullptr, B0h + 512, B0l + 512, mask_[u], nullptr, F,
          512, NB0, D, NB0, 32, 24, 1, 12, 8, 0L, 0L, 0L, 0L, 0L, 0L);
      if (u == 0) {
        // P[b] (+)= Xall[:, 0:3584] @ B0^T (3p, K=3584); h==0: pure store.
        // BN=96: grid 16x32 = 512 = exactly 2 blocks/CU; rects 8x8
        if (h == 0) {
          gemm_split3<96, false, false, false, false><<<512, 256, 0, stream>>>(
              Xallh, Xalll, B0h, B0l, P, nullptr, nullptr, nullptr, nullptr, 0,
              NB0, NALL, NB0, F, 32, 8, 2, 8, 8,
              (long)S * NALL, 0L, 0L, 0L, (long)S * F, 0L);
        } else {
          gemm_split3<96, true, false, false, false><<<512, 256, 0, stream>>>(
              Xallh, Xalll, B0h, B0l, P, nullptr, nullptr, nullptr, nullptr, 0,
              NB0, NALL, NB0, F, 32, 8, 2, 8, 8,
              (long)S * NALL, 0L, 0L, 0L, (long)S * F, 0L);
        }
      } else {
        // P[b] += Xall[:, 3584:6656] @ vw_u1^T  (3p, K=3072, ldb=3584)
        gemm_split3<96, true, false, false, false><<<512, 256, 0, stream>>>(
            Xallh + NB0, Xalll + NB0, B0h + 512, B0l + 512,
            P, nullptr, nullptr, nullptr, nullptr, 0,
            3072, NALL, NB0, F, 32, 8, 2, 8, 8,
            (long)S * NALL, 0L, 0L, 0L, (long)S * F, 0L);
      }
    }
  }

  // ---- tail: dec_w transpose (into dead Xall region), topk in-place, recon ----
  transpose_dw<<<dim3(F / 32, D / 32), 256, 0, stream>>>(dec_w, dec_wT);
  topk_fused<<<B * S, 256, 0, stream>>>(P, bias0, evec, ln, topv, topi);
  recon_kernel<<<B * S, 256, 0, stream>>>(topv, topi, dec_wT, b_dec, out_recon);
}